// Round 1
// baseline (430.375 us; speedup 1.0000x reference)
//
#include <hip/hip_runtime.h>
#include <hip/hip_bf16.h>

// ---------------- types / constants ----------------
typedef __bf16 bf16x8 __attribute__((ext_vector_type(8)));
typedef float f32x4 __attribute__((ext_vector_type(4)));
typedef unsigned short u16;
typedef u16 u16x8 __attribute__((ext_vector_type(8)));

#define T_N 2048
#define H_N 2048
#define NH 8
#define NKV 4
#define HD 256
#define BATCH 4
#define SEQ 512
#define SCAL 0.0625f   // 256^-0.5
#define EPS_ 1e-6f

typedef const __attribute__((address_space(1))) void* gptr1;
typedef __attribute__((address_space(3))) void* lptr3;

__device__ __forceinline__ u16 f2bf(float f) {
  union { float f; unsigned u; } x; x.f = f;
  unsigned r = x.u + 0x7fffu + ((x.u >> 16) & 1u);
  return (u16)(r >> 16);
}

__device__ __forceinline__ void gload_lds16(const void* g, void* l) {
  __builtin_amdgcn_global_load_lds((gptr1)g, (lptr3)l, 16, 0, 0);
}

// ---------------- f32 -> bf16 convert (vectorized) ----------------
__global__ void k_f32_to_bf16(const float* __restrict__ in, u16* __restrict__ out, int n8) {
  int i = blockIdx.x * blockDim.x + threadIdx.x;
  if (i >= n8) return;
  const float4* p = (const float4*)in + (size_t)i * 2;
  float4 v0 = p[0], v1 = p[1];
  u16x8 o;
  o[0] = f2bf(v0.x); o[1] = f2bf(v0.y); o[2] = f2bf(v0.z); o[3] = f2bf(v0.w);
  o[4] = f2bf(v1.x); o[5] = f2bf(v1.y); o[6] = f2bf(v1.z); o[7] = f2bf(v1.w);
  *(u16x8*)(out + (size_t)i * 8) = o;
}

// ---------------- a+b -> bf16 ----------------
__global__ void k_sum_bf16(const float* __restrict__ a, const float* __restrict__ b,
                           u16* __restrict__ out, int n8) {
  int i = blockIdx.x * blockDim.x + threadIdx.x;
  if (i >= n8) return;
  const float4* pa = (const float4*)a + (size_t)i * 2;
  const float4* pb = (const float4*)b + (size_t)i * 2;
  float4 a0 = pa[0], a1 = pa[1], b0 = pb[0], b1 = pb[1];
  u16x8 o;
  o[0] = f2bf(a0.x + b0.x); o[1] = f2bf(a0.y + b0.y); o[2] = f2bf(a0.z + b0.z); o[3] = f2bf(a0.w + b0.w);
  o[4] = f2bf(a1.x + b1.x); o[5] = f2bf(a1.y + b1.y); o[6] = f2bf(a1.z + b1.z); o[7] = f2bf(a1.w + b1.w);
  *(u16x8*)(out + (size_t)i * 8) = o;
}

// ---------------- transpose f32 (R,C) -> bf16 (C,R) ----------------
__global__ void k_transpose_bf16(const float* __restrict__ in, u16* __restrict__ out, int R, int C) {
  __shared__ float tile[32][33];
  const int tx = threadIdx.x, ty = threadIdx.y;
  const int c0 = blockIdx.x * 32, r0 = blockIdx.y * 32;
  #pragma unroll
  for (int i = ty; i < 32; i += 8) tile[i][tx] = in[(size_t)(r0 + i) * C + c0 + tx];
  __syncthreads();
  #pragma unroll
  for (int i = ty; i < 32; i += 8) out[(size_t)(c0 + i) * R + r0 + tx] = f2bf(tile[tx][i]);
}

// ---------------- bf16 GEMM: C[M,N] = A[M,K] * Bt[N,K]^T (m97 structure) ----------------
__global__ __launch_bounds__(256) void k_gemm_bt(const u16* __restrict__ A, const u16* __restrict__ Bt,
                                                 float* __restrict__ C, int M, int N, int K) {
  __shared__ u16 a_lds[128 * 32];
  __shared__ u16 b_lds[128 * 32];
  const int tid = threadIdx.x;
  const int lane = tid & 63;
  const int wid = tid >> 6;
  const int l15 = lane & 15, lg = lane >> 4;
  const int bm = blockIdx.x, bn = blockIdx.y;
  const int wm = wid >> 1, wn = wid & 1;
  f32x4 acc[4][4];
  #pragma unroll
  for (int i = 0; i < 4; i++)
    #pragma unroll
    for (int j = 0; j < 4; j++) acc[i][j] = (f32x4){0.f, 0.f, 0.f, 0.f};
  const int e = tid * 8;                // element offset within 64-row half-tile
  const int row0 = e >> 5, col0 = e & 31;
  const u16* Ab = A + (size_t)bm * 128 * K;
  const u16* Bb = Bt + (size_t)bn * 128 * K;
  for (int kt = 0; kt < K; kt += 32) {
    __syncthreads();
    gload_lds16(Ab + (size_t)row0 * K + kt + col0, &a_lds[e]);
    gload_lds16(Ab + (size_t)(row0 + 64) * K + kt + col0, &a_lds[e + 2048]);
    gload_lds16(Bb + (size_t)row0 * K + kt + col0, &b_lds[e]);
    gload_lds16(Bb + (size_t)(row0 + 64) * K + kt + col0, &b_lds[e + 2048]);
    __syncthreads();
    bf16x8 af[4], bfr[4];
    #pragma unroll
    for (int m = 0; m < 4; m++) af[m] = *(const bf16x8*)&a_lds[(wm * 64 + m * 16 + l15) * 32 + lg * 8];
    #pragma unroll
    for (int n = 0; n < 4; n++) bfr[n] = *(const bf16x8*)&b_lds[(wn * 64 + n * 16 + l15) * 32 + lg * 8];
    #pragma unroll
    for (int m = 0; m < 4; m++)
      #pragma unroll
      for (int n = 0; n < 4; n++)
        acc[m][n] = __builtin_amdgcn_mfma_f32_16x16x32_bf16(af[m], bfr[n], acc[m][n], 0, 0, 0);
  }
  const int crow = bm * 128 + wm * 64;
  const int ccol = bn * 128 + wn * 64;
  #pragma unroll
  for (int m = 0; m < 4; m++)
    #pragma unroll
    for (int n = 0; n < 4; n++)
      #pragma unroll
      for (int r = 0; r < 4; r++)
        C[(size_t)(crow + m * 16 + lg * 4 + r) * N + ccol + n * 16 + l15] = acc[m][n][r];
}

// ---------------- prep: rmsnorm + rope + scaling + v transpose ----------------
__global__ __launch_bounds__(256) void k_prep(
    const float* __restrict__ qkv, const float* __restrict__ qkve,
    const float* __restrict__ cosT, const float* __restrict__ sinT,
    const float* __restrict__ qnw, const float* __restrict__ knw,
    u16* __restrict__ q_rope, u16* __restrict__ qc,
    u16* __restrict__ k_rope, u16* __restrict__ vT,
    u16* __restrict__ k_enc, u16* __restrict__ vT_enc) {
  const int t = blockIdx.x;
  const int lane = threadIdx.x & 63;
  const int wid = threadIdx.x >> 6;
  const int b = t >> 9, s = t & 511;
  const int d0 = lane, d1 = lane + 64, d2 = lane + 128, d3 = lane + 192;
  const float c0 = cosT[t * HD + d0], c1 = cosT[t * HD + d1], c2 = cosT[t * HD + d2], c3 = cosT[t * HD + d3];
  const float s0 = sinT[t * HD + d0], s1 = sinT[t * HD + d1], s2 = sinT[t * HD + d2], s3 = sinT[t * HD + d3];
  const float qw0 = 1.f + qnw[d0], qw1 = 1.f + qnw[d1], qw2 = 1.f + qnw[d2], qw3 = 1.f + qnw[d3];
  const float kw0 = 1.f + knw[d0], kw1 = 1.f + knw[d1], kw2 = 1.f + knw[d2], kw3 = 1.f + knw[d3];

  // q heads (2 per wave)
  for (int hh = 0; hh < 2; hh++) {
    const int h = wid + hh * 4;
    const float* x = qkv + (size_t)t * 4096 + h * HD;
    float a0 = x[d0], a1 = x[d1], a2 = x[d2], a3 = x[d3];
    float ss = a0 * a0 + a1 * a1 + a2 * a2 + a3 * a3;
    #pragma unroll
    for (int o = 1; o < 64; o <<= 1) ss += __shfl_xor(ss, o);
    const float rms = rsqrtf(ss * (1.f / HD) + EPS_);
    const float n0 = a0 * rms * qw0, n1 = a1 * rms * qw1, n2 = a2 * rms * qw2, n3 = a3 * rms * qw3;
    const size_t qb = ((size_t)t * NH + h) * HD;
    qc[qb + d0] = f2bf(n0 * SCAL); qc[qb + d1] = f2bf(n1 * SCAL);
    qc[qb + d2] = f2bf(n2 * SCAL); qc[qb + d3] = f2bf(n3 * SCAL);
    q_rope[qb + d0] = f2bf((n0 * c0 - n2 * s0) * SCAL);
    q_rope[qb + d1] = f2bf((n1 * c1 - n3 * s1) * SCAL);
    q_rope[qb + d2] = f2bf((n2 * c2 + n0 * s2) * SCAL);
    q_rope[qb + d3] = f2bf((n3 * c3 + n1 * s3) * SCAL);
  }
  // self k head (1 per wave)
  {
    const float* x = qkv + (size_t)t * 4096 + 2048 + wid * HD;
    float a0 = x[d0], a1 = x[d1], a2 = x[d2], a3 = x[d3];
    float ss = a0 * a0 + a1 * a1 + a2 * a2 + a3 * a3;
    #pragma unroll
    for (int o = 1; o < 64; o <<= 1) ss += __shfl_xor(ss, o);
    const float rms = rsqrtf(ss * (1.f / HD) + EPS_);
    const float n0 = a0 * rms * kw0, n1 = a1 * rms * kw1, n2 = a2 * rms * kw2, n3 = a3 * rms * kw3;
    const size_t kb = ((size_t)t * NKV + wid) * HD;
    k_rope[kb + d0] = f2bf(n0 * c0 - n2 * s0);
    k_rope[kb + d1] = f2bf(n1 * c1 - n3 * s1);
    k_rope[kb + d2] = f2bf(n2 * c2 + n0 * s2);
    k_rope[kb + d3] = f2bf(n3 * c3 + n1 * s3);
  }
  // self v -> transposed [b][kvh][d][s]
  {
    const float* x = qkv + (size_t)t * 4096 + 3072 + wid * HD;
    const size_t vb = (size_t)(b * NKV + wid) * HD;
    vT[(vb + d0) * SEQ + s] = f2bf(x[d0]);
    vT[(vb + d1) * SEQ + s] = f2bf(x[d1]);
    vT[(vb + d2) * SEQ + s] = f2bf(x[d2]);
    vT[(vb + d3) * SEQ + s] = f2bf(x[d3]);
  }
  // encoder k (norm, no rope)
  {
    const float* x = qkve + (size_t)t * 2048 + wid * HD;
    float a0 = x[d0], a1 = x[d1], a2 = x[d2], a3 = x[d3];
    float ss = a0 * a0 + a1 * a1 + a2 * a2 + a3 * a3;
    #pragma unroll
    for (int o = 1; o < 64; o <<= 1) ss += __shfl_xor(ss, o);
    const float rms = rsqrtf(ss * (1.f / HD) + EPS_);
    const size_t kb = ((size_t)t * NKV + wid) * HD;
    k_enc[kb + d0] = f2bf(a0 * rms * kw0);
    k_enc[kb + d1] = f2bf(a1 * rms * kw1);
    k_enc[kb + d2] = f2bf(a2 * rms * kw2);
    k_enc[kb + d3] = f2bf(a3 * rms * kw3);
  }
  // encoder v -> transposed
  {
    const float* x = qkve + (size_t)t * 2048 + 1024 + wid * HD;
    const size_t vb = (size_t)(b * NKV + wid) * HD;
    vT_enc[(vb + d0) * SEQ + s] = f2bf(x[d0]);
    vT_enc[(vb + d1) * SEQ + s] = f2bf(x[d1]);
    vT_enc[(vb + d2) * SEQ + s] = f2bf(x[d2]);
    vT_enc[(vb + d3) * SEQ + s] = f2bf(x[d3]);
  }
}

// ---------------- fused flash attention (self z<4, cross z>=4) ----------------
__global__ __launch_bounds__(256) void k_attn(
    const u16* __restrict__ q_rope, const u16* __restrict__ qc,
    const u16* __restrict__ k_rope, const u16* __restrict__ k_enc,
    const u16* __restrict__ vT, const u16* __restrict__ vT_enc,
    float* __restrict__ o_self, float* __restrict__ o_cross) {
  __shared__ u16 p_lds[4][16][72];   // padded rows: conflict-free ds_read_b128
  const int qt = blockIdx.x;
  const int h = blockIdx.y;
  const int which = blockIdx.z >> 2;  // 0=self(causal), 1=cross
  const int b = blockIdx.z & 3;
  const int kvh = h >> 1;
  const int lane = threadIdx.x & 63;
  const int wid = threadIdx.x >> 6;
  const int l15 = lane & 15;
  const int lg = lane >> 4;
  const int qrow = qt * 64 + wid * 16;
  const u16* Qg = which ? qc : q_rope;
  const u16* Kg = which ? k_enc : k_rope;
  const u16* Vg = which ? vT_enc : vT;
  float* Og = which ? o_cross : o_self;

  // Q fragments in registers: 16 rows x 256 d
  bf16x8 qf[8];
  {
    const size_t base = ((size_t)(b * SEQ + qrow + l15) * NH + h) * HD + lg * 8;
    #pragma unroll
    for (int c = 0; c < 8; c++) qf[c] = *(const bf16x8*)(Qg + base + c * 32);
  }
  float m[4], lsum[4];
  f32x4 O[16];
  #pragma unroll
  for (int r = 0; r < 4; r++) { m[r] = -INFINITY; lsum[r] = 0.f; }
  #pragma unroll
  for (int d = 0; d < 16; d++) O[d] = (f32x4){0.f, 0.f, 0.f, 0.f};

  const int nkt = which ? 8 : (qt + 1);
  for (int kt = 0; kt < nkt; kt++) {
    // scores: 16 q-rows x 64 keys
    f32x4 sc[4];
    #pragma unroll
    for (int n = 0; n < 4; n++) sc[n] = (f32x4){0.f, 0.f, 0.f, 0.f};
    #pragma unroll
    for (int n = 0; n < 4; n++) {
      const size_t kb = ((size_t)(b * SEQ + kt * 64 + n * 16 + l15) * NKV + kvh) * HD + lg * 8;
      #pragma unroll
      for (int c = 0; c < 8; c++) {
        bf16x8 kf = *(const bf16x8*)(Kg + kb + c * 32);
        sc[n] = __builtin_amdgcn_mfma_f32_16x16x32_bf16(qf[c], kf, sc[n], 0, 0, 0);
      }
    }
    if (!which && kt == qt) {   // diagonal tile causal mask
      #pragma unroll
      for (int n = 0; n < 4; n++) {
        const int key = kt * 64 + n * 16 + l15;
        #pragma unroll
        for (int r = 0; r < 4; r++)
          if (key > qrow + lg * 4 + r) sc[n][r] = -INFINITY;
      }
    }
    // online softmax
    float pmax[4];
    #pragma unroll
    for (int r = 0; r < 4; r++)
      pmax[r] = fmaxf(fmaxf(sc[0][r], sc[1][r]), fmaxf(sc[2][r], sc[3][r]));
    #pragma unroll
    for (int off = 1; off < 16; off <<= 1)
      #pragma unroll
      for (int r = 0; r < 4; r++) pmax[r] = fmaxf(pmax[r], __shfl_xor(pmax[r], off));
    float scal[4];
    #pragma unroll
    for (int r = 0; r < 4; r++) {
      const float mn = fmaxf(m[r], pmax[r]);
      scal[r] = __expf(m[r] - mn);
      m[r] = mn;
    }
    float ps[4] = {0.f, 0.f, 0.f, 0.f};
    #pragma unroll
    for (int n = 0; n < 4; n++)
      #pragma unroll
      for (int r = 0; r < 4; r++) {
        const float p = __expf(sc[n][r] - m[r]);
        ps[r] += p;
        p_lds[wid][lg * 4 + r][n * 16 + l15] = f2bf(p);
      }
    #pragma unroll
    for (int off = 1; off < 16; off <<= 1)
      #pragma unroll
      for (int r = 0; r < 4; r++) ps[r] += __shfl_xor(ps[r], off);
    #pragma unroll
    for (int r = 0; r < 4; r++) lsum[r] = lsum[r] * scal[r] + ps[r];
    #pragma unroll
    for (int d = 0; d < 16; d++)
      #pragma unroll
      for (int r = 0; r < 4; r++) O[d][r] *= scal[r];
    // P back as MFMA A-fragments (per-wave LDS region, in-order per wave)
    bf16x8 pa0 = *(const bf16x8*)&p_lds[wid][l15][lg * 8];
    bf16x8 pa1 = *(const bf16x8*)&p_lds[wid][l15][32 + lg * 8];
    #pragma unroll
    for (int d = 0; d < 16; d++) {
      const size_t vb = ((size_t)((b * NKV + kvh) * HD + d * 16 + l15)) * SEQ + kt * 64 + lg * 8;
      O[d] = __builtin_amdgcn_mfma_f32_16x16x32_bf16(pa0, *(const bf16x8*)(Vg + vb), O[d], 0, 0, 0);
      O[d] = __builtin_amdgcn_mfma_f32_16x16x32_bf16(pa1, *(const bf16x8*)(Vg + vb + 32), O[d], 0, 0, 0);
    }
  }
  #pragma unroll
  for (int r = 0; r < 4; r++) lsum[r] = 1.f / lsum[r];
  #pragma unroll
  for (int d = 0; d < 16; d++)
    #pragma unroll
    for (int r = 0; r < 4; r++) {
      const size_t o = (size_t)(b * SEQ + qrow + lg * 4 + r) * (NH * HD) + h * HD + d * 16 + l15;
      Og[o] = O[d][r] * lsum[r];
    }
}

// ---------------- launcher ----------------
extern "C" void kernel_launch(void* const* d_in, const int* in_sizes, int n_in,
                              void* d_out, int out_size, void* d_ws, size_t ws_size,
                              hipStream_t stream) {
  (void)in_sizes; (void)n_in; (void)out_size; (void)ws_size;
  const float* hidden  = (const float*)d_in[0];
  const float* encoder = (const float*)d_in[1];
  const float* cosT    = (const float*)d_in[2];
  const float* sinT    = (const float*)d_in[3];
  const float* w_qkv   = (const float*)d_in[4];
  const float* w_o     = (const float*)d_in[5];
  const float* qnw     = (const float*)d_in[6];
  const float* knw     = (const float*)d_in[7];
  float* out = (float*)d_out;
  char* ws = (char*)d_ws;

  // ws layout (lifetime-overlapped), 120 MB total
  u16*  hid_bf = (u16*) (ws + (0ull  << 20));   // 8 MB   [dies after gemm1a]
  u16*  enc_bf = (u16*) (ws + (8ull  << 20));   // 8 MB   [dies after gemm1b]
  u16*  wqkvT  = (u16*) (ws + (16ull << 20));   // 16 MB  [dies after gemm1b]
  u16*  woT    = (u16*) (ws + (32ull << 20));   // 8 MB
  float* qkv   = (float*)(ws + (40ull << 20));  // 32 MB  [dies after prep]
  float* qkve  = (float*)(ws + (72ull << 20));  // 16 MB
  u16*  q_rope = (u16*) (ws + (88ull << 20));   // 8 MB
  u16*  qc     = (u16*) (ws + (96ull << 20));   // 8 MB
  u16*  k_rope = (u16*) (ws + (104ull << 20));  // 4 MB
  u16*  vT     = (u16*) (ws + (108ull << 20));  // 4 MB
  u16*  k_enc  = (u16*) (ws + (112ull << 20));  // 4 MB
  u16*  vT_enc = (u16*) (ws + (116ull << 20));  // 4 MB
  float* attnf  = (float*)(ws + (0ull  << 20)); // 16 MB  (overlays hid/enc_bf)
  float* attnf2 = (float*)(ws + (16ull << 20)); // 16 MB  (overlays wqkvT)
  u16*  attnbf  = (u16*) (ws + (40ull << 20));  // 8 MB   (overlays qkv)

  const int n8 = T_N * H_N / 8;
  k_f32_to_bf16<<<n8 / 256, 256, 0, stream>>>(hidden, hid_bf, n8);
  k_f32_to_bf16<<<n8 / 256, 256, 0, stream>>>(encoder, enc_bf, n8);
  k_transpose_bf16<<<dim3(4096 / 32, 2048 / 32), dim3(32, 8), 0, stream>>>(w_qkv, wqkvT, 2048, 4096);
  k_transpose_bf16<<<dim3(2048 / 32, 2048 / 32), dim3(32, 8), 0, stream>>>(w_o, woT, 2048, 2048);
  k_gemm_bt<<<dim3(16, 32), 256, 0, stream>>>(hid_bf, wqkvT, qkv, 2048, 4096, 2048);
  k_gemm_bt<<<dim3(16, 16), 256, 0, stream>>>(enc_bf, wqkvT + (size_t)2048 * 2048, qkve, 2048, 2048, 2048);
  k_prep<<<T_N, 256, 0, stream>>>(qkv, qkve, cosT, sinT, qnw, knw,
                                  q_rope, qc, k_rope, vT, k_enc, vT_enc);
  k_attn<<<dim3(8, 8, 8), 256, 0, stream>>>(q_rope, qc, k_rope, k_enc, vT, vT_enc, attnf, attnf2);
  k_sum_bf16<<<n8 / 256, 256, 0, stream>>>(attnf, attnf2, attnbf, n8);
  k_gemm_bt<<<dim3(16, 16), 256, 0, stream>>>(attnbf, woT, out, 2048, 2048, 2048);
}

// Round 2
// 271.832 us; speedup vs baseline: 1.5832x; 1.5832x over previous
//
#include <hip/hip_runtime.h>
#include <hip/hip_bf16.h>

// ---------------- types / constants ----------------
typedef __bf16 bf16x8 __attribute__((ext_vector_type(8)));
typedef float f32x4 __attribute__((ext_vector_type(4)));
typedef unsigned short u16;
typedef u16 u16x8 __attribute__((ext_vector_type(8)));

#define T_N 2048
#define H_N 2048
#define NH 8
#define NKV 4
#define HD 256
#define BATCH 4
#define SEQ 512
#define SCAL 0.0625f   // 256^-0.5
#define EPS_ 1e-6f

typedef const __attribute__((address_space(1))) void* gptr1;
typedef __attribute__((address_space(3))) void* lptr3;

__device__ __forceinline__ u16 f2bf(float f) {
  union { float f; unsigned u; } x; x.f = f;
  unsigned r = x.u + 0x7fffu + ((x.u >> 16) & 1u);
  return (u16)(r >> 16);
}

__device__ __forceinline__ void gload_lds16(const void* g, void* l) {
  __builtin_amdgcn_global_load_lds((gptr1)g, (lptr3)l, 16, 0, 0);
}

// ---------------- f32 -> bf16 convert (vectorized) ----------------
__global__ void k_f32_to_bf16(const float* __restrict__ in, u16* __restrict__ out, int n8) {
  int i = blockIdx.x * blockDim.x + threadIdx.x;
  if (i >= n8) return;
  const float4* p = (const float4*)in + (size_t)i * 2;
  float4 v0 = p[0], v1 = p[1];
  u16x8 o;
  o[0] = f2bf(v0.x); o[1] = f2bf(v0.y); o[2] = f2bf(v0.z); o[3] = f2bf(v0.w);
  o[4] = f2bf(v1.x); o[5] = f2bf(v1.y); o[6] = f2bf(v1.z); o[7] = f2bf(v1.w);
  *(u16x8*)(out + (size_t)i * 8) = o;
}

// ---------------- transpose f32 (R,C) -> bf16 (C,R) ----------------
__global__ void k_transpose_bf16(const float* __restrict__ in, u16* __restrict__ out, int R, int C) {
  __shared__ float tile[32][33];
  const int tx = threadIdx.x, ty = threadIdx.y;
  const int c0 = blockIdx.x * 32, r0 = blockIdx.y * 32;
  #pragma unroll
  for (int i = ty; i < 32; i += 8) tile[i][tx] = in[(size_t)(r0 + i) * C + c0 + tx];
  __syncthreads();
  #pragma unroll
  for (int i = ty; i < 32; i += 8) out[(size_t)(c0 + i) * R + r0 + tx] = f2bf(tile[tx][i]);
}

// ---------------- bf16 GEMM: C[M,N] = A[M,K] * Bt[N,K]^T (m97 structure) ----------------
__global__ __launch_bounds__(256) void k_gemm_bt(const u16* __restrict__ A, const u16* __restrict__ Bt,
                                                 float* __restrict__ C, int M, int N, int K) {
  __shared__ u16 a_lds[128 * 32];
  __shared__ u16 b_lds[128 * 32];
  const int tid = threadIdx.x;
  const int lane = tid & 63;
  const int wid = tid >> 6;
  const int l15 = lane & 15, lg = lane >> 4;
  const int bm = blockIdx.x, bn = blockIdx.y;
  const int wm = wid >> 1, wn = wid & 1;
  f32x4 acc[4][4];
  #pragma unroll
  for (int i = 0; i < 4; i++)
    #pragma unroll
    for (int j = 0; j < 4; j++) acc[i][j] = (f32x4){0.f, 0.f, 0.f, 0.f};
  const int e = tid * 8;                // element offset within 64-row half-tile
  const int row0 = e >> 5, col0 = e & 31;
  const u16* Ab = A + (size_t)bm * 128 * K;
  const u16* Bb = Bt + (size_t)bn * 128 * K;
  for (int kt = 0; kt < K; kt += 32) {
    __syncthreads();
    gload_lds16(Ab + (size_t)row0 * K + kt + col0, &a_lds[e]);
    gload_lds16(Ab + (size_t)(row0 + 64) * K + kt + col0, &a_lds[e + 2048]);
    gload_lds16(Bb + (size_t)row0 * K + kt + col0, &b_lds[e]);
    gload_lds16(Bb + (size_t)(row0 + 64) * K + kt + col0, &b_lds[e + 2048]);
    __syncthreads();
    bf16x8 af[4], bfr[4];
    #pragma unroll
    for (int m = 0; m < 4; m++) af[m] = *(const bf16x8*)&a_lds[(wm * 64 + m * 16 + l15) * 32 + lg * 8];
    #pragma unroll
    for (int n = 0; n < 4; n++) bfr[n] = *(const bf16x8*)&b_lds[(wn * 64 + n * 16 + l15) * 32 + lg * 8];
    #pragma unroll
    for (int m = 0; m < 4; m++)
      #pragma unroll
      for (int n = 0; n < 4; n++)
        acc[m][n] = __builtin_amdgcn_mfma_f32_16x16x32_bf16(af[m], bfr[n], acc[m][n], 0, 0, 0);
  }
  const int crow = bm * 128 + wm * 64;
  const int ccol = bn * 128 + wn * 64;
  #pragma unroll
  for (int m = 0; m < 4; m++)
    #pragma unroll
    for (int n = 0; n < 4; n++)
      #pragma unroll
      for (int r = 0; r < 4; r++)
        C[(size_t)(crow + m * 16 + lg * 4 + r) * N + ccol + n * 16 + l15] = acc[m][n][r];
}

// ---------------- prep: rmsnorm + rope + scaling + v transpose ----------------
__global__ __launch_bounds__(256) void k_prep(
    const float* __restrict__ qkv, const float* __restrict__ qkve,
    const float* __restrict__ cosT, const float* __restrict__ sinT,
    const float* __restrict__ qnw, const float* __restrict__ knw,
    u16* __restrict__ q_rope, u16* __restrict__ qc,
    u16* __restrict__ k_rope, u16* __restrict__ vT,
    u16* __restrict__ k_enc, u16* __restrict__ vT_enc) {
  const int t = blockIdx.x;
  const int lane = threadIdx.x & 63;
  const int wid = threadIdx.x >> 6;
  const int b = t >> 9, s = t & 511;
  const int d0 = lane, d1 = lane + 64, d2 = lane + 128, d3 = lane + 192;
  const float c0 = cosT[t * HD + d0], c1 = cosT[t * HD + d1], c2 = cosT[t * HD + d2], c3 = cosT[t * HD + d3];
  const float s0 = sinT[t * HD + d0], s1 = sinT[t * HD + d1], s2 = sinT[t * HD + d2], s3 = sinT[t * HD + d3];
  const float qw0 = 1.f + qnw[d0], qw1 = 1.f + qnw[d1], qw2 = 1.f + qnw[d2], qw3 = 1.f + qnw[d3];
  const float kw0 = 1.f + knw[d0], kw1 = 1.f + knw[d1], kw2 = 1.f + knw[d2], kw3 = 1.f + knw[d3];

  // q heads (2 per wave)
  for (int hh = 0; hh < 2; hh++) {
    const int h = wid + hh * 4;
    const float* x = qkv + (size_t)t * 4096 + h * HD;
    float a0 = x[d0], a1 = x[d1], a2 = x[d2], a3 = x[d3];
    float ss = a0 * a0 + a1 * a1 + a2 * a2 + a3 * a3;
    #pragma unroll
    for (int o = 1; o < 64; o <<= 1) ss += __shfl_xor(ss, o);
    const float rms = rsqrtf(ss * (1.f / HD) + EPS_);
    const float n0 = a0 * rms * qw0, n1 = a1 * rms * qw1, n2 = a2 * rms * qw2, n3 = a3 * rms * qw3;
    const size_t qb = ((size_t)t * NH + h) * HD;
    qc[qb + d0] = f2bf(n0 * SCAL); qc[qb + d1] = f2bf(n1 * SCAL);
    qc[qb + d2] = f2bf(n2 * SCAL); qc[qb + d3] = f2bf(n3 * SCAL);
    q_rope[qb + d0] = f2bf((n0 * c0 - n2 * s0) * SCAL);
    q_rope[qb + d1] = f2bf((n1 * c1 - n3 * s1) * SCAL);
    q_rope[qb + d2] = f2bf((n2 * c2 + n0 * s2) * SCAL);
    q_rope[qb + d3] = f2bf((n3 * c3 + n1 * s3) * SCAL);
  }
  // self k head (1 per wave)
  {
    const float* x = qkv + (size_t)t * 4096 + 2048 + wid * HD;
    float a0 = x[d0], a1 = x[d1], a2 = x[d2], a3 = x[d3];
    float ss = a0 * a0 + a1 * a1 + a2 * a2 + a3 * a3;
    #pragma unroll
    for (int o = 1; o < 64; o <<= 1) ss += __shfl_xor(ss, o);
    const float rms = rsqrtf(ss * (1.f / HD) + EPS_);
    const float n0 = a0 * rms * kw0, n1 = a1 * rms * kw1, n2 = a2 * rms * kw2, n3 = a3 * rms * kw3;
    const size_t kb = ((size_t)t * NKV + wid) * HD;
    k_rope[kb + d0] = f2bf(n0 * c0 - n2 * s0);
    k_rope[kb + d1] = f2bf(n1 * c1 - n3 * s1);
    k_rope[kb + d2] = f2bf(n2 * c2 + n0 * s2);
    k_rope[kb + d3] = f2bf(n3 * c3 + n1 * s3);
  }
  // self v -> transposed [b][kvh][d][s]
  {
    const float* x = qkv + (size_t)t * 4096 + 3072 + wid * HD;
    const size_t vb = (size_t)(b * NKV + wid) * HD;
    vT[(vb + d0) * SEQ + s] = f2bf(x[d0]);
    vT[(vb + d1) * SEQ + s] = f2bf(x[d1]);
    vT[(vb + d2) * SEQ + s] = f2bf(x[d2]);
    vT[(vb + d3) * SEQ + s] = f2bf(x[d3]);
  }
  // encoder k (norm, no rope)
  {
    const float* x = qkve + (size_t)t * 2048 + wid * HD;
    float a0 = x[d0], a1 = x[d1], a2 = x[d2], a3 = x[d3];
    float ss = a0 * a0 + a1 * a1 + a2 * a2 + a3 * a3;
    #pragma unroll
    for (int o = 1; o < 64; o <<= 1) ss += __shfl_xor(ss, o);
    const float rms = rsqrtf(ss * (1.f / HD) + EPS_);
    const size_t kb = ((size_t)t * NKV + wid) * HD;
    k_enc[kb + d0] = f2bf(a0 * rms * kw0);
    k_enc[kb + d1] = f2bf(a1 * rms * kw1);
    k_enc[kb + d2] = f2bf(a2 * rms * kw2);
    k_enc[kb + d3] = f2bf(a3 * rms * kw3);
  }
  // encoder v -> transposed
  {
    const float* x = qkve + (size_t)t * 2048 + 1024 + wid * HD;
    const size_t vb = (size_t)(b * NKV + wid) * HD;
    vT_enc[(vb + d0) * SEQ + s] = f2bf(x[d0]);
    vT_enc[(vb + d1) * SEQ + s] = f2bf(x[d1]);
    vT_enc[(vb + d2) * SEQ + s] = f2bf(x[d2]);
    vT_enc[(vb + d3) * SEQ + s] = f2bf(x[d3]);
  }
}

// ---------------- fused flash attention: self (causal) + cross in one block ----------------
// grid (qt=8, h=8, b=4), 256 threads. K/V tiles LDS-staged (double-buffered,
// XOR-swizzled both sides per rule #21), T3-minimum 2-phase pipeline.
__global__ __launch_bounds__(256) void k_attn(
    const u16* __restrict__ q_rope, const u16* __restrict__ qc,
    const u16* __restrict__ k_rope, const u16* __restrict__ k_enc,
    const u16* __restrict__ vT, const u16* __restrict__ vT_enc,
    u16* __restrict__ out_bf) {
  __shared__ u16 k_lds[2][64 * 256];   // [key][d] rows of 512B, chunk16 swizzled c^= (key&7)
  __shared__ u16 v_lds[2][256 * 64];   // [d][s] rows of 128B, chunk16 swizzled c^= (d&7)
  __shared__ u16 p_lds[4][16][72];     // P bounce, padded rows

  const int qt = blockIdx.x;
  const int h = blockIdx.y;
  const int b = blockIdx.z;
  const int kvh = h >> 1;
  const int tid = threadIdx.x;
  const int lane = tid & 63;
  const int wid = tid >> 6;
  const int l15 = lane & 15;
  const int lg = lane >> 4;
  const int swk = l15 & 7;
  const int qrow = qt * 64 + wid * 16;

  const int nself = qt + 1;
  const int total = nself + 8;

  // ---- staging (cooperative, all 256 threads) ----
  // K row/chunk per thread: idx = j*256+tid; row = idx>>5, c = idx&31, src chunk = c ^ (row&7)
  // V row/chunk per thread: idx = j*256+tid; row = idx>>3, c = idx&7,  src chunk = c ^ (row&7)
  #define STAGE_TILE(buf, it_)                                                        \
    {                                                                                 \
      const int it = (it_);                                                           \
      const int kt_ = (it < nself) ? it : (it - nself);                               \
      const u16* Kg_ = (it < nself) ? k_rope : k_enc;                                 \
      const u16* Vg_ = (it < nself) ? vT : vT_enc;                                    \
      _Pragma("unroll")                                                               \
      for (int j = 0; j < 8; j++) {                                                   \
        const int idx = j * 256 + tid;                                                \
        const int kr = idx >> 5, kc = idx & 31;                                       \
        const int cs = kc ^ (kr & 7);                                                 \
        gload_lds16(Kg_ + ((size_t)((b * SEQ + kt_ * 64 + kr) * NKV + kvh)) * HD + cs * 8, \
                    &k_lds[buf][idx * 8]);                                            \
      }                                                                               \
      _Pragma("unroll")                                                               \
      for (int j = 0; j < 8; j++) {                                                   \
        const int idx = j * 256 + tid;                                                \
        const int dr = idx >> 3, dc = idx & 7;                                        \
        const int cs = dc ^ (dr & 7);                                                 \
        gload_lds16(Vg_ + ((size_t)((b * NKV + kvh) * HD + dr)) * SEQ + kt_ * 64 + cs * 8, \
                    &v_lds[buf][idx * 8]);                                            \
      }                                                                               \
    }

  // ---- Q fragments (self-phase Q first) ----
  bf16x8 qf[8];
  {
    const size_t base = ((size_t)(b * SEQ + qrow + l15) * NH + h) * HD + lg * 8;
    #pragma unroll
    for (int c = 0; c < 8; c++) qf[c] = *(const bf16x8*)(q_rope + base + c * 32);
  }

  float m[4], lsum[4];
  f32x4 O[16], Os[16];
  #pragma unroll
  for (int r = 0; r < 4; r++) { m[r] = -INFINITY; lsum[r] = 0.f; }
  #pragma unroll
  for (int d = 0; d < 16; d++) { O[d] = (f32x4){0.f, 0.f, 0.f, 0.f}; Os[d] = O[d]; }

  STAGE_TILE(0, 0);
  int cur = 0;

  for (int it = 0; it < total; ++it) {
    __syncthreads();                       // drains this wave's vmcnt -> buf[cur] ready; buf[cur^1] free
    if (it + 1 < total) STAGE_TILE(cur ^ 1, it + 1);

    if (it == nself) {
      // finalize self into Os, reset state, switch Q to qc
      #pragma unroll
      for (int r = 0; r < 4; r++) {
        const float inv = 1.f / lsum[r];
        #pragma unroll
        for (int d = 0; d < 16; d++) Os[d][r] = O[d][r] * inv;
        m[r] = -INFINITY; lsum[r] = 0.f;
      }
      #pragma unroll
      for (int d = 0; d < 16; d++) O[d] = (f32x4){0.f, 0.f, 0.f, 0.f};
      const size_t base = ((size_t)(b * SEQ + qrow + l15) * NH + h) * HD + lg * 8;
      #pragma unroll
      for (int c = 0; c < 8; c++) qf[c] = *(const bf16x8*)(qc + base + c * 32);
    }

    const u16* kl = k_lds[cur];
    const u16* vl = v_lds[cur];

    // ---- QK^T: 16 q-rows x 64 keys ----
    f32x4 sc[4];
    #pragma unroll
    for (int n = 0; n < 4; n++) sc[n] = (f32x4){0.f, 0.f, 0.f, 0.f};
    #pragma unroll
    for (int n = 0; n < 4; n++) {
      const int krow = n * 16 + l15;
      #pragma unroll
      for (int c = 0; c < 8; c++) {
        bf16x8 kf = *(const bf16x8*)&kl[krow * 256 + (((c * 4 + lg) ^ swk) * 8)];
        sc[n] = __builtin_amdgcn_mfma_f32_16x16x32_bf16(qf[c], kf, sc[n], 0, 0, 0);
      }
    }
    if (it == qt && it < nself) {          // causal diagonal tile (self phase only)
      #pragma unroll
      for (int n = 0; n < 4; n++) {
        const int key = qt * 64 + n * 16 + l15;
        #pragma unroll
        for (int r = 0; r < 4; r++)
          if (key > qrow + lg * 4 + r) sc[n][r] = -INFINITY;
      }
    }
    // ---- online softmax ----
    float pmax[4];
    #pragma unroll
    for (int r = 0; r < 4; r++)
      pmax[r] = fmaxf(fmaxf(sc[0][r], sc[1][r]), fmaxf(sc[2][r], sc[3][r]));
    #pragma unroll
    for (int off = 1; off < 16; off <<= 1)
      #pragma unroll
      for (int r = 0; r < 4; r++) pmax[r] = fmaxf(pmax[r], __shfl_xor(pmax[r], off));
    float scal[4];
    #pragma unroll
    for (int r = 0; r < 4; r++) {
      const float mn = fmaxf(m[r], pmax[r]);
      scal[r] = __expf(m[r] - mn);
      m[r] = mn;
    }
    float ps[4] = {0.f, 0.f, 0.f, 0.f};
    #pragma unroll
    for (int n = 0; n < 4; n++)
      #pragma unroll
      for (int r = 0; r < 4; r++) {
        const float p = __expf(sc[n][r] - m[r]);
        ps[r] += p;
        p_lds[wid][lg * 4 + r][n * 16 + l15] = f2bf(p);
      }
    #pragma unroll
    for (int off = 1; off < 16; off <<= 1)
      #pragma unroll
      for (int r = 0; r < 4; r++) ps[r] += __shfl_xor(ps[r], off);
    #pragma unroll
    for (int r = 0; r < 4; r++) lsum[r] = lsum[r] * scal[r] + ps[r];
    #pragma unroll
    for (int d = 0; d < 16; d++)
      #pragma unroll
      for (int r = 0; r < 4; r++) O[d][r] *= scal[r];
    // ---- PV ----
    bf16x8 pa0 = *(const bf16x8*)&p_lds[wid][l15][lg * 8];
    bf16x8 pa1 = *(const bf16x8*)&p_lds[wid][l15][32 + lg * 8];
    #pragma unroll
    for (int d = 0; d < 16; d++) {
      const int vrow = d * 16 + l15;
      bf16x8 v0 = *(const bf16x8*)&vl[vrow * 64 + ((lg ^ swk) * 8)];
      bf16x8 v1 = *(const bf16x8*)&vl[vrow * 64 + (((lg + 4) ^ swk) * 8)];
      O[d] = __builtin_amdgcn_mfma_f32_16x16x32_bf16(pa0, v0, O[d], 0, 0, 0);
      O[d] = __builtin_amdgcn_mfma_f32_16x16x32_bf16(pa1, v1, O[d], 0, 0, 0);
    }
    cur ^= 1;
  }
  #undef STAGE_TILE

  // ---- epilogue: out = self + cross, bf16 ----
  #pragma unroll
  for (int r = 0; r < 4; r++) {
    const float inv = 1.f / lsum[r];
    const size_t rowb = (size_t)(b * SEQ + qrow + lg * 4 + r) * (NH * HD) + h * HD;
    #pragma unroll
    for (int d = 0; d < 16; d++)
      out_bf[rowb + d * 16 + l15] = f2bf(Os[d][r] + O[d][r] * inv);
  }
}

// ---------------- launcher ----------------
extern "C" void kernel_launch(void* const* d_in, const int* in_sizes, int n_in,
                              void* d_out, int out_size, void* d_ws, size_t ws_size,
                              hipStream_t stream) {
  (void)in_sizes; (void)n_in; (void)out_size; (void)ws_size;
  const float* hidden  = (const float*)d_in[0];
  const float* encoder = (const float*)d_in[1];
  const float* cosT    = (const float*)d_in[2];
  const float* sinT    = (const float*)d_in[3];
  const float* w_qkv   = (const float*)d_in[4];
  const float* w_o     = (const float*)d_in[5];
  const float* qnw     = (const float*)d_in[6];
  const float* knw     = (const float*)d_in[7];
  float* out = (float*)d_out;
  char* ws = (char*)d_ws;

  // ws layout (lifetime-overlapped)
  u16*  hid_bf = (u16*) (ws + (0ull  << 20));   // 8 MB   [dies after gemm1a]
  u16*  enc_bf = (u16*) (ws + (8ull  << 20));   // 8 MB   [dies after gemm1b]
  u16*  wqkvT  = (u16*) (ws + (16ull << 20));   // 16 MB  [dies after gemm1b]
  u16*  woT    = (u16*) (ws + (32ull << 20));   // 8 MB
  float* qkv   = (float*)(ws + (40ull << 20));  // 32 MB  [dies after prep]
  float* qkve  = (float*)(ws + (72ull << 20));  // 16 MB  [dies after prep]
  u16*  q_rope = (u16*) (ws + (88ull << 20));   // 8 MB
  u16*  qc     = (u16*) (ws + (96ull << 20));   // 8 MB
  u16*  k_rope = (u16*) (ws + (104ull << 20));  // 4 MB
  u16*  vT     = (u16*) (ws + (108ull << 20));  // 4 MB
  u16*  k_enc  = (u16*) (ws + (112ull << 20));  // 4 MB
  u16*  vT_enc = (u16*) (ws + (116ull << 20));  // 4 MB
  u16*  attnbf = (u16*) (ws + (40ull << 20));   // 8 MB   (overlays qkv)

  const int n8 = T_N * H_N / 8;
  k_f32_to_bf16<<<n8 / 256, 256, 0, stream>>>(hidden, hid_bf, n8);
  k_f32_to_bf16<<<n8 / 256, 256, 0, stream>>>(encoder, enc_bf, n8);
  k_transpose_bf16<<<dim3(4096 / 32, 2048 / 32), dim3(32, 8), 0, stream>>>(w_qkv, wqkvT, 2048, 4096);
  k_transpose_bf16<<<dim3(2048 / 32, 2048 / 32), dim3(32, 8), 0, stream>>>(w_o, woT, 2048, 2048);
  k_gemm_bt<<<dim3(16, 32), 256, 0, stream>>>(hid_bf, wqkvT, qkv, 2048, 4096, 2048);
  k_gemm_bt<<<dim3(16, 16), 256, 0, stream>>>(enc_bf, wqkvT + (size_t)2048 * 2048, qkve, 2048, 2048, 2048);
  k_prep<<<T_N, 256, 0, stream>>>(qkv, qkve, cosT, sinT, qnw, knw,
                                  q_rope, qc, k_rope, vT, k_enc, vT_enc);
  k_attn<<<dim3(8, 8, 4), 256, 0, stream>>>(q_rope, qc, k_rope, k_enc, vT, vT_enc, attnbf);
  k_gemm_bt<<<dim3(16, 16), 256, 0, stream>>>(attnbf, woT, out, 2048, 2048, 2048);
}

// Round 6
// 263.046 us; speedup vs baseline: 1.6361x; 1.0334x over previous
//
#include <hip/hip_runtime.h>
#include <hip/hip_bf16.h>

// ---------------- types / constants ----------------
typedef __bf16 bf16x8 __attribute__((ext_vector_type(8)));
typedef float f32x4 __attribute__((ext_vector_type(4)));
typedef unsigned short u16;
typedef u16 u16x8 __attribute__((ext_vector_type(8)));

#define T_N 2048
#define NH 8
#define NKV 4
#define HD 256
#define SEQ 512
#define SCAL 0.0625f   // 256^-0.5
#define EPS_ 1e-6f

typedef const __attribute__((address_space(1))) void* gptr1;
typedef __attribute__((address_space(3))) void* lptr3;

__device__ __forceinline__ u16 f2bf(float f) {
  union { float f; unsigned u; } x; x.f = f;
  unsigned r = x.u + 0x7fffu + ((x.u >> 16) & 1u);
  return (u16)(r >> 16);
}
__device__ __forceinline__ void gload_lds16(const void* g, void* l) {
  __builtin_amdgcn_global_load_lds((gptr1)g, (lptr3)l, 16, 0, 0);
}

// ---------------- f32 -> bf16 convert (vectorized) [round-2 verbatim] ----------------
__global__ void k_f32_to_bf16(const float* __restrict__ in, u16* __restrict__ out, int n8) {
  int i = blockIdx.x * blockDim.x + threadIdx.x;
  if (i >= n8) return;
  const float4* p = (const float4*)in + (size_t)i * 2;
  float4 v0 = p[0], v1 = p[1];
  u16x8 o;
  o[0] = f2bf(v0.x); o[1] = f2bf(v0.y); o[2] = f2bf(v0.z); o[3] = f2bf(v0.w);
  o[4] = f2bf(v1.x); o[5] = f2bf(v1.y); o[6] = f2bf(v1.z); o[7] = f2bf(v1.w);
  *(u16x8*)(out + (size_t)i * 8) = o;
}

// ---------------- transpose f32 (R,C) -> bf16 (C,R) [round-2 verbatim] ----------------
__global__ void k_transpose_bf16(const float* __restrict__ in, u16* __restrict__ out, int R, int C) {
  __shared__ float tile[32][33];
  const int tx = threadIdx.x, ty = threadIdx.y;
  const int c0 = blockIdx.x * 32, r0 = blockIdx.y * 32;
  #pragma unroll
  for (int i = ty; i < 32; i += 8) tile[i][tx] = in[(size_t)(r0 + i) * C + c0 + tx];
  __syncthreads();
  #pragma unroll
  for (int i = ty; i < 32; i += 8) out[(size_t)(c0 + i) * R + r0 + tx] = f2bf(tile[tx][i]);
}

// ---------------- bf16 GEMM: C[M,N] = A[M,K] * Bt[N,K]^T [round-2 verbatim] ----------------
__global__ __launch_bounds__(256) void k_gemm_bt(const u16* __restrict__ A, const u16* __restrict__ Bt,
                                                 float* __restrict__ C, int M, int N, int K) {
  __shared__ u16 a_lds[128 * 32];
  __shared__ u16 b_lds[128 * 32];
  const int tid = threadIdx.x;
  const int lane = tid & 63;
  const int wid = tid >> 6;
  const int l15 = lane & 15, lg = lane >> 4;
  const int bm = blockIdx.x, bn = blockIdx.y;
  const int wm = wid >> 1, wn = wid & 1;
  f32x4 acc[4][4];
  #pragma unroll
  for (int i = 0; i < 4; i++)
    #pragma unroll
    for (int j = 0; j < 4; j++) acc[i][j] = (f32x4){0.f, 0.f, 0.f, 0.f};
  const int e = tid * 8;                // element offset within 64-row half-tile
  const int row0 = e >> 5, col0 = e & 31;
  const u16* Ab = A + (size_t)bm * 128 * K;
  const u16* Bb = Bt + (size_t)bn * 128 * K;
  for (int kt = 0; kt < K; kt += 32) {
    __syncthreads();
    gload_lds16(Ab + (size_t)row0 * K + kt + col0, &a_lds[e]);
    gload_lds16(Ab + (size_t)(row0 + 64) * K + kt + col0, &a_lds[e + 2048]);
    gload_lds16(Bb + (size_t)row0 * K + kt + col0, &b_lds[e]);
    gload_lds16(Bb + (size_t)(row0 + 64) * K + kt + col0, &b_lds[e + 2048]);
    __syncthreads();
    bf16x8 af[4], bfr[4];
    #pragma unroll
    for (int m = 0; m < 4; m++) af[m] = *(const bf16x8*)&a_lds[(wm * 64 + m * 16 + l15) * 32 + lg * 8];
    #pragma unroll
    for (int n = 0; n < 4; n++) bfr[n] = *(const bf16x8*)&b_lds[(wn * 64 + n * 16 + l15) * 32 + lg * 8];
    #pragma unroll
    for (int m = 0; m < 4; m++)
      #pragma unroll
      for (int n = 0; n < 4; n++)
        acc[m][n] = __builtin_amdgcn_mfma_f32_16x16x32_bf16(af[m], bfr[n], acc[m][n], 0, 0, 0);
  }
  const int crow = bm * 128 + wm * 64;
  const int ccol = bn * 128 + wn * 64;
  #pragma unroll
  for (int m = 0; m < 4; m++)
    #pragma unroll
    for (int n = 0; n < 4; n++)
      #pragma unroll
      for (int r = 0; r < 4; r++)
        C[(size_t)(crow + m * 16 + lg * 4 + r) * N + ccol + n * 16 + l15] = acc[m][n][r];
}

// ---------------- prep: rmsnorm + rope + scaling + v transpose ----------------
// round-2 body; ONLY diff: enc output lives inside the big C at row stride 4096
// (qkve points at C + 2048*4096 + 2048; enc k at +0, enc v at +1024 within that).
__global__ __launch_bounds__(256) void k_prep(
    const float* __restrict__ qkv, const float* __restrict__ qkve,
    const float* __restrict__ cosT, const float* __restrict__ sinT,
    const float* __restrict__ qnw, const float* __restrict__ knw,
    u16* __restrict__ q_rope, u16* __restrict__ qc,
    u16* __restrict__ k_rope, u16* __restrict__ vT,
    u16* __restrict__ k_enc, u16* __restrict__ vT_enc) {
  const int t = blockIdx.x;
  const int lane = threadIdx.x & 63;
  const int wid = threadIdx.x >> 6;
  const int b = t >> 9, s = t & 511;
  const int d0 = lane, d1 = lane + 64, d2 = lane + 128, d3 = lane + 192;
  const float c0 = cosT[t * HD + d0], c1 = cosT[t * HD + d1], c2 = cosT[t * HD + d2], c3 = cosT[t * HD + d3];
  const float s0 = sinT[t * HD + d0], s1 = sinT[t * HD + d1], s2 = sinT[t * HD + d2], s3 = sinT[t * HD + d3];
  const float qw0 = 1.f + qnw[d0], qw1 = 1.f + qnw[d1], qw2 = 1.f + qnw[d2], qw3 = 1.f + qnw[d3];
  const float kw0 = 1.f + knw[d0], kw1 = 1.f + knw[d1], kw2 = 1.f + knw[d2], kw3 = 1.f + knw[d3];

  // q heads (2 per wave)
  for (int hh = 0; hh < 2; hh++) {
    const int h = wid + hh * 4;
    const float* x = qkv + (size_t)t * 4096 + h * HD;
    float a0 = x[d0], a1 = x[d1], a2 = x[d2], a3 = x[d3];
    float ss = a0 * a0 + a1 * a1 + a2 * a2 + a3 * a3;
    #pragma unroll
    for (int o = 1; o < 64; o <<= 1) ss += __shfl_xor(ss, o);
    const float rms = rsqrtf(ss * (1.f / HD) + EPS_);
    const float n0 = a0 * rms * qw0, n1 = a1 * rms * qw1, n2 = a2 * rms * qw2, n3 = a3 * rms * qw3;
    const size_t qb = ((size_t)t * NH + h) * HD;
    qc[qb + d0] = f2bf(n0 * SCAL); qc[qb + d1] = f2bf(n1 * SCAL);
    qc[qb + d2] = f2bf(n2 * SCAL); qc[qb + d3] = f2bf(n3 * SCAL);
    q_rope[qb + d0] = f2bf((n0 * c0 - n2 * s0) * SCAL);
    q_rope[qb + d1] = f2bf((n1 * c1 - n3 * s1) * SCAL);
    q_rope[qb + d2] = f2bf((n2 * c2 + n0 * s2) * SCAL);
    q_rope[qb + d3] = f2bf((n3 * c3 + n1 * s3) * SCAL);
  }
  // self k head (1 per wave)
  {
    const float* x = qkv + (size_t)t * 4096 + 2048 + wid * HD;
    float a0 = x[d0], a1 = x[d1], a2 = x[d2], a3 = x[d3];
    float ss = a0 * a0 + a1 * a1 + a2 * a2 + a3 * a3;
    #pragma unroll
    for (int o = 1; o < 64; o <<= 1) ss += __shfl_xor(ss, o);
    const float rms = rsqrtf(ss * (1.f / HD) + EPS_);
    const float n0 = a0 * rms * kw0, n1 = a1 * rms * kw1, n2 = a2 * rms * kw2, n3 = a3 * rms * kw3;
    const size_t kb = ((size_t)t * NKV + wid) * HD;
    k_rope[kb + d0] = f2bf(n0 * c0 - n2 * s0);
    k_rope[kb + d1] = f2bf(n1 * c1 - n3 * s1);
    k_rope[kb + d2] = f2bf(n2 * c2 + n0 * s2);
    k_rope[kb + d3] = f2bf(n3 * c3 + n1 * s3);
  }
  // self v -> transposed [b][kvh][d][s]
  {
    const float* x = qkv + (size_t)t * 4096 + 3072 + wid * HD;
    const size_t vb = (size_t)(b * NKV + wid) * HD;
    vT[(vb + d0) * SEQ + s] = f2bf(x[d0]);
    vT[(vb + d1) * SEQ + s] = f2bf(x[d1]);
    vT[(vb + d2) * SEQ + s] = f2bf(x[d2]);
    vT[(vb + d3) * SEQ + s] = f2bf(x[d3]);
  }
  // encoder k (norm, no rope) -- row stride 4096 (lives inside big C)
  {
    const float* x = qkve + (size_t)t * 4096 + wid * HD;
    float a0 = x[d0], a1 = x[d1], a2 = x[d2], a3 = x[d3];
    float ss = a0 * a0 + a1 * a1 + a2 * a2 + a3 * a3;
    #pragma unroll
    for (int o = 1; o < 64; o <<= 1) ss += __shfl_xor(ss, o);
    const float rms = rsqrtf(ss * (1.f / HD) + EPS_);
    const size_t kb = ((size_t)t * NKV + wid) * HD;
    k_enc[kb + d0] = f2bf(a0 * rms * kw0);
    k_enc[kb + d1] = f2bf(a1 * rms * kw1);
    k_enc[kb + d2] = f2bf(a2 * rms * kw2);
    k_enc[kb + d3] = f2bf(a3 * rms * kw3);
  }
  // encoder v -> transposed -- row stride 4096
  {
    const float* x = qkve + (size_t)t * 4096 + 1024 + wid * HD;
    const size_t vb = (size_t)(b * NKV + wid) * HD;
    vT_enc[(vb + d0) * SEQ + s] = f2bf(x[d0]);
    vT_enc[(vb + d1) * SEQ + s] = f2bf(x[d1]);
    vT_enc[(vb + d2) * SEQ + s] = f2bf(x[d2]);
    vT_enc[(vb + d3) * SEQ + s] = f2bf(x[d3]);
  }
}

// ---------------- fused flash attention [round-2 verbatim] ----------------
__global__ __launch_bounds__(256) void k_attn(
    const u16* __restrict__ q_rope, const u16* __restrict__ qc,
    const u16* __restrict__ k_rope, const u16* __restrict__ k_enc,
    const u16* __restrict__ vT, const u16* __restrict__ vT_enc,
    u16* __restrict__ out_bf) {
  __shared__ u16 k_lds[2][64 * 256];
  __shared__ u16 v_lds[2][256 * 64];
  __shared__ u16 p_lds[4][16][72];

  const int qt = blockIdx.x;
  const int h = blockIdx.y;
  const int b = blockIdx.z;
  const int kvh = h >> 1;
  const int tid = threadIdx.x;
  const int lane = tid & 63;
  const int wid = tid >> 6;
  const int l15 = lane & 15;
  const int lg = lane >> 4;
  const int swk = l15 & 7;
  const int qrow = qt * 64 + wid * 16;

  const int nself = qt + 1;
  const int total = nself + 8;

  #define STAGE_TILE(buf, it_)                                                        \
    {                                                                                 \
      const int it = (it_);                                                           \
      const int kt_ = (it < nself) ? it : (it - nself);                               \
      const u16* Kg_ = (it < nself) ? k_rope : k_enc;                                 \
      const u16* Vg_ = (it < nself) ? vT : vT_enc;                                    \
      _Pragma("unroll")                                                               \
      for (int j = 0; j < 8; j++) {                                                   \
        const int idx = j * 256 + tid;                                                \
        const int kr = idx >> 5, kc = idx & 31;                                       \
        const int cs = kc ^ (kr & 7);                                                 \
        gload_lds16(Kg_ + ((size_t)((b * SEQ + kt_ * 64 + kr) * NKV + kvh)) * HD + cs * 8, \
                    &k_lds[buf][idx * 8]);                                            \
      }                                                                               \
      _Pragma("unroll")                                                               \
      for (int j = 0; j < 8; j++) {                                                   \
        const int idx = j * 256 + tid;                                                \
        const int dr = idx >> 3, dc = idx & 7;                                        \
        const int cs = dc ^ (dr & 7);                                                 \
        gload_lds16(Vg_ + ((size_t)((b * NKV + kvh) * HD + dr)) * SEQ + kt_ * 64 + cs * 8, \
                    &v_lds[buf][idx * 8]);                                            \
      }                                                                               \
    }

  bf16x8 qf[8];
  {
    const size_t base = ((size_t)(b * SEQ + qrow + l15) * NH + h) * HD + lg * 8;
    #pragma unroll
    for (int c = 0; c < 8; c++) qf[c] = *(const bf16x8*)(q_rope + base + c * 32);
  }

  float m[4], lsum[4];
  f32x4 O[16], Os[16];
  #pragma unroll
  for (int r = 0; r < 4; r++) { m[r] = -INFINITY; lsum[r] = 0.f; }
  #pragma unroll
  for (int d = 0; d < 16; d++) { O[d] = (f32x4){0.f, 0.f, 0.f, 0.f}; Os[d] = O[d]; }

  STAGE_TILE(0, 0);
  int cur = 0;

  for (int it = 0; it < total; ++it) {
    __syncthreads();
    if (it + 1 < total) STAGE_TILE(cur ^ 1, it + 1);

    if (it == nself) {
      #pragma unroll
      for (int r = 0; r < 4; r++) {
        const float inv = 1.f / lsum[r];
        #pragma unroll
        for (int d = 0; d < 16; d++) Os[d][r] = O[d][r] * inv;
        m[r] = -INFINITY; lsum[r] = 0.f;
      }
      #pragma unroll
      for (int d = 0; d < 16; d++) O[d] = (f32x4){0.f, 0.f, 0.f, 0.f};
      const size_t base = ((size_t)(b * SEQ + qrow + l15) * NH + h) * HD + lg * 8;
      #pragma unroll
      for (int c = 0; c < 8; c++) qf[c] = *(const bf16x8*)(qc + base + c * 32);
    }

    const u16* kl = k_lds[cur];
    const u16* vl = v_lds[cur];

    f32x4 sc[4];
    #pragma unroll
    for (int n = 0; n < 4; n++) sc[n] = (f32x4){0.f, 0.f, 0.f, 0.f};
    #pragma unroll
    for (int n = 0; n < 4; n++) {
      const int krow = n * 16 + l15;
      #pragma unroll
      for (int c = 0; c < 8; c++) {
        bf16x8 kf = *(const bf16x8*)&kl[krow * 256 + (((c * 4 + lg) ^ swk) * 8)];
        sc[n] = __builtin_amdgcn_mfma_f32_16x16x32_bf16(qf[c], kf, sc[n], 0, 0, 0);
      }
    }
    if (it == qt && it < nself) {
      #pragma unroll
      for (int n = 0; n < 4; n++) {
        const int key = qt * 64 + n * 16 + l15;
        #pragma unroll
        for (int r = 0; r < 4; r++)
          if (key > qrow + lg * 4 + r) sc[n][r] = -INFINITY;
      }
    }
    float pmax[4];
    #pragma unroll
    for (int r = 0; r < 4; r++)
      pmax[r] = fmaxf(fmaxf(sc[0][r], sc[1][r]), fmaxf(sc[2][r], sc[3][r]));
    #pragma unroll
    for (int off = 1; off < 16; off <<= 1)
      #pragma unroll
      for (int r = 0; r < 4; r++) pmax[r] = fmaxf(pmax[r], __shfl_xor(pmax[r], off));
    float scal[4];
    #pragma unroll
    for (int r = 0; r < 4; r++) {
      const float mn = fmaxf(m[r], pmax[r]);
      scal[r] = __expf(m[r] - mn);
      m[r] = mn;
    }
    float ps[4] = {0.f, 0.f, 0.f, 0.f};
    #pragma unroll
    for (int n = 0; n < 4; n++)
      #pragma unroll
      for (int r = 0; r < 4; r++) {
        const float p = __expf(sc[n][r] - m[r]);
        ps[r] += p;
        p_lds[wid][lg * 4 + r][n * 16 + l15] = f2bf(p);
      }
    #pragma unroll
    for (int off = 1; off < 16; off <<= 1)
      #pragma unroll
      for (int r = 0; r < 4; r++) ps[r] += __shfl_xor(ps[r], off);
    #pragma unroll
    for (int r = 0; r < 4; r++) lsum[r] = lsum[r] * scal[r] + ps[r];
    #pragma unroll
    for (int d = 0; d < 16; d++)
      #pragma unroll
      for (int r = 0; r < 4; r++) O[d][r] *= scal[r];
    bf16x8 pa0 = *(const bf16x8*)&p_lds[wid][l15][lg * 8];
    bf16x8 pa1 = *(const bf16x8*)&p_lds[wid][l15][32 + lg * 8];
    #pragma unroll
    for (int d = 0; d < 16; d++) {
      const int vrow = d * 16 + l15;
      bf16x8 v0 = *(const bf16x8*)&vl[vrow * 64 + ((lg ^ swk) * 8)];
      bf16x8 v1 = *(const bf16x8*)&vl[vrow * 64 + (((lg + 4) ^ swk) * 8)];
      O[d] = __builtin_amdgcn_mfma_f32_16x16x32_bf16(pa0, v0, O[d], 0, 0, 0);
      O[d] = __builtin_amdgcn_mfma_f32_16x16x32_bf16(pa1, v1, O[d], 0, 0, 0);
    }
    cur ^= 1;
  }
  #undef STAGE_TILE

  #pragma unroll
  for (int r = 0; r < 4; r++) {
    const float inv = 1.f / lsum[r];
    const size_t rowb = (size_t)(b * SEQ + qrow + lg * 4 + r) * (NH * HD) + h * HD;
    #pragma unroll
    for (int d = 0; d < 16; d++)
      out_bf[rowb + d * 16 + l15] = f2bf(Os[d][r] + O[d][r] * inv);
  }
}

// ---------------- launcher ----------------
extern "C" void kernel_launch(void* const* d_in, const int* in_sizes, int n_in,
                              void* d_out, int out_size, void* d_ws, size_t ws_size,
                              hipStream_t stream) {
  (void)in_sizes; (void)n_in; (void)out_size; (void)ws_size;
  const float* hidden  = (const float*)d_in[0];
  const float* encoder = (const float*)d_in[1];
  const float* cosT    = (const float*)d_in[2];
  const float* sinT    = (const float*)d_in[3];
  const float* w_qkv   = (const float*)d_in[4];
  const float* w_o     = (const float*)d_in[5];
  const float* qnw     = (const float*)d_in[6];
  const float* knw     = (const float*)d_in[7];
  float* out = (float*)d_out;
  char* ws = (char*)d_ws;

  // ws layout (MB offsets), max touch 104 MB (< proven-safe 120 MB)
  u16*  hid_bf = (u16*) (ws + (0ull  << 20));   // 8 MB   } contiguous: A2 = [hidden; encoder]
  u16*  enc_bf = (u16*) (ws + (8ull  << 20));   // 8 MB   }   (4096 x 2048 bf16)
  u16*  wqkvT  = (u16*) (ws + (16ull << 20));   // 16 MB  [dies after big GEMM]
  u16*  woT    = (u16*) (ws + (32ull << 20));   // 8 MB   [lives to out-proj]
  float* qkvC  = (float*)(ws + (40ull << 20));  // 64 MB  (4096x4096 f32) [dies after prep]
  u16*  q_rope = (u16*) (ws + (0ull  << 20));   // 8 MB   (overlays dead hid_bf)
  u16*  qc     = (u16*) (ws + (8ull  << 20));   // 8 MB   (overlays dead enc_bf)
  u16*  k_rope = (u16*) (ws + (16ull << 20));   // 4 MB   (overlays dead wqkvT)
  u16*  vT     = (u16*) (ws + (20ull << 20));   // 4 MB
  u16*  k_enc  = (u16*) (ws + (24ull << 20));   // 4 MB
  u16*  vT_enc = (u16*) (ws + (28ull << 20));   // 4 MB
  u16*  attnbf = (u16*) (ws + (40ull << 20));   // 8 MB   (overlays dead qkvC head)

  const int n8 = T_N * 2048 / 8;
  k_f32_to_bf16<<<n8 / 256, 256, 0, stream>>>(hidden, hid_bf, n8);
  k_f32_to_bf16<<<n8 / 256, 256, 0, stream>>>(encoder, enc_bf, n8);
  k_transpose_bf16<<<dim3(4096 / 32, 2048 / 32), dim3(32, 8), 0, stream>>>(w_qkv, wqkvT, 2048, 4096);
  k_transpose_bf16<<<dim3(2048 / 32, 2048 / 32), dim3(32, 8), 0, stream>>>(w_o, woT, 2048, 2048);
  // one big GEMM: [hidden; encoder] (4096x2048) @ w_qkv^T -> qkvC (4096x4096)
  k_gemm_bt<<<dim3(32, 32), 256, 0, stream>>>(hid_bf, wqkvT, qkvC, 4096, 4096, 2048);
  // enc rows' kv outputs live at qkvC[2048 + t][2048 + c], row stride 4096
  k_prep<<<T_N, 256, 0, stream>>>(qkvC, qkvC + (size_t)2048 * 4096 + 2048,
                                  cosT, sinT, qnw, knw,
                                  q_rope, qc, k_rope, vT, k_enc, vT_enc);
  k_attn<<<dim3(8, 8, 4), 256, 0, stream>>>(q_rope, qc, k_rope, k_enc, vT, vT_enc, attnbf);
  k_gemm_bt<<<dim3(16, 16), 256, 0, stream>>>(attnbf, woT, out, 2048, 2048, 2048);
}

// Round 8
// 249.159 us; speedup vs baseline: 1.7273x; 1.0557x over previous
//
#include <hip/hip_runtime.h>
#include <hip/hip_bf16.h>

// ---------------- types / constants ----------------
typedef __bf16 bf16x8 __attribute__((ext_vector_type(8)));
typedef float f32x4 __attribute__((ext_vector_type(4)));
typedef unsigned short u16;
typedef u16 u16x8 __attribute__((ext_vector_type(8)));

#define T_N 2048
#define NH 8
#define NKV 4
#define HD 256
#define SEQ 512
#define SCAL 0.0625f   // 256^-0.5
#define EPS_ 1e-6f

typedef const __attribute__((address_space(1))) void* gptr1;
typedef __attribute__((address_space(3))) void* lptr3;

__device__ __forceinline__ u16 f2bf(float f) {
  union { float f; unsigned u; } x; x.f = f;
  unsigned r = x.u + 0x7fffu + ((x.u >> 16) & 1u);
  return (u16)(r >> 16);
}
__device__ __forceinline__ void gload_lds16(const void* g, void* l) {
  __builtin_amdgcn_global_load_lds((gptr1)g, (lptr3)l, 16, 0, 0);
}

// ---------------- f32 -> bf16 convert (vectorized) [round-6 verbatim] ----------------
__global__ void k_f32_to_bf16(const float* __restrict__ in, u16* __restrict__ out, int n8) {
  int i = blockIdx.x * blockDim.x + threadIdx.x;
  if (i >= n8) return;
  const float4* p = (const float4*)in + (size_t)i * 2;
  float4 v0 = p[0], v1 = p[1];
  u16x8 o;
  o[0] = f2bf(v0.x); o[1] = f2bf(v0.y); o[2] = f2bf(v0.z); o[3] = f2bf(v0.w);
  o[4] = f2bf(v1.x); o[5] = f2bf(v1.y); o[6] = f2bf(v1.z); o[7] = f2bf(v1.w);
  *(u16x8*)(out + (size_t)i * 8) = o;
}

// ---------------- transpose f32 (R,C) -> bf16 (C,R) [round-6 verbatim] ----------------
__global__ void k_transpose_bf16(const float* __restrict__ in, u16* __restrict__ out, int R, int C) {
  __shared__ float tile[32][33];
  const int tx = threadIdx.x, ty = threadIdx.y;
  const int c0 = blockIdx.x * 32, r0 = blockIdx.y * 32;
  #pragma unroll
  for (int i = ty; i < 32; i += 8) tile[i][tx] = in[(size_t)(r0 + i) * C + c0 + tx];
  __syncthreads();
  #pragma unroll
  for (int i = ty; i < 32; i += 8) out[(size_t)(c0 + i) * R + r0 + tx] = f2bf(tile[tx][i]);
}

// ---------------- bf16 GEMM: C[M,N] = A[M,K] * Bt[N,K]^T [round-6 verbatim] ----------------
__global__ __launch_bounds__(256) void k_gemm_bt(const u16* __restrict__ A, const u16* __restrict__ Bt,
                                                 float* __restrict__ C, int M, int N, int K) {
  __shared__ u16 a_lds[128 * 32];
  __shared__ u16 b_lds[128 * 32];
  const int tid = threadIdx.x;
  const int lane = tid & 63;
  const int wid = tid >> 6;
  const int l15 = lane & 15, lg = lane >> 4;
  const int bm = blockIdx.x, bn = blockIdx.y;
  const int wm = wid >> 1, wn = wid & 1;
  f32x4 acc[4][4];
  #pragma unroll
  for (int i = 0; i < 4; i++)
    #pragma unroll
    for (int j = 0; j < 4; j++) acc[i][j] = (f32x4){0.f, 0.f, 0.f, 0.f};
  const int e = tid * 8;                // element offset within 64-row half-tile
  const int row0 = e >> 5, col0 = e & 31;
  const u16* Ab = A + (size_t)bm * 128 * K;
  const u16* Bb = Bt + (size_t)bn * 128 * K;
  for (int kt = 0; kt < K; kt += 32) {
    __syncthreads();
    gload_lds16(Ab + (size_t)row0 * K + kt + col0, &a_lds[e]);
    gload_lds16(Ab + (size_t)(row0 + 64) * K + kt + col0, &a_lds[e + 2048]);
    gload_lds16(Bb + (size_t)row0 * K + kt + col0, &b_lds[e]);
    gload_lds16(Bb + (size_t)(row0 + 64) * K + kt + col0, &b_lds[e + 2048]);
    __syncthreads();
    bf16x8 af[4], bfr[4];
    #pragma unroll
    for (int m = 0; m < 4; m++) af[m] = *(const bf16x8*)&a_lds[(wm * 64 + m * 16 + l15) * 32 + lg * 8];
    #pragma unroll
    for (int n = 0; n < 4; n++) bfr[n] = *(const bf16x8*)&b_lds[(wn * 64 + n * 16 + l15) * 32 + lg * 8];
    #pragma unroll
    for (int m = 0; m < 4; m++)
      #pragma unroll
      for (int n = 0; n < 4; n++)
        acc[m][n] = __builtin_amdgcn_mfma_f32_16x16x32_bf16(af[m], bfr[n], acc[m][n], 0, 0, 0);
  }
  const int crow = bm * 128 + wm * 64;
  const int ccol = bn * 128 + wn * 64;
  #pragma unroll
  for (int m = 0; m < 4; m++)
    #pragma unroll
    for (int n = 0; n < 4; n++)
      #pragma unroll
      for (int r = 0; r < 4; r++)
        C[(size_t)(crow + m * 16 + lg * 4 + r) * N + ccol + n * 16 + l15] = acc[m][n][r];
}

// ---------------- out-projection GEMM, 128x64 tile (2 blocks/CU) ----------------
// C[2048,2048] = A[2048,2048] * Bt[2048,2048]^T. grid (16,32), 4 waves,
// wave grid 2(M)x2(N), wave tile 64x32. Branch-free; staging arithmetic is the
// proven per-lane LDS = tid*16B linear contract.
__global__ __launch_bounds__(256) void k_gemm_n64(const u16* __restrict__ A, const u16* __restrict__ Bt,
                                                  float* __restrict__ C) {
  __shared__ u16 a_lds[128 * 32];
  __shared__ u16 b_lds[64 * 32];
  const int N = 2048, K = 2048;
  const int tid = threadIdx.x;
  const int lane = tid & 63;
  const int wid = tid >> 6;
  const int l15 = lane & 15, lg = lane >> 4;
  const int bm = blockIdx.x, bn = blockIdx.y;
  const int wm = wid >> 1, wn = wid & 1;
  f32x4 acc[4][2];
  #pragma unroll
  for (int i = 0; i < 4; i++)
    #pragma unroll
    for (int j = 0; j < 2; j++) acc[i][j] = (f32x4){0.f, 0.f, 0.f, 0.f};
  const int e = tid * 8;                    // 2048 elems = 64 rows x 32 cols
  const int row0 = e >> 5, col0 = e & 31;   // row0 0..63
  const u16* Ab = A + (size_t)bm * 128 * K;
  const u16* Bb = Bt + (size_t)bn * 64 * K;
  for (int kt = 0; kt < K; kt += 32) {
    __syncthreads();
    gload_lds16(Ab + (size_t)row0 * K + kt + col0, &a_lds[e]);
    gload_lds16(Ab + (size_t)(row0 + 64) * K + kt + col0, &a_lds[e + 2048]);
    gload_lds16(Bb + (size_t)row0 * K + kt + col0, &b_lds[e]);
    __syncthreads();
    bf16x8 af[4], bfr[2];
    #pragma unroll
    for (int m = 0; m < 4; m++) af[m] = *(const bf16x8*)&a_lds[(wm * 64 + m * 16 + l15) * 32 + lg * 8];
    #pragma unroll
    for (int n = 0; n < 2; n++) bfr[n] = *(const bf16x8*)&b_lds[(wn * 32 + n * 16 + l15) * 32 + lg * 8];
    #pragma unroll
    for (int m = 0; m < 4; m++)
      #pragma unroll
      for (int n = 0; n < 2; n++)
        acc[m][n] = __builtin_amdgcn_mfma_f32_16x16x32_bf16(af[m], bfr[n], acc[m][n], 0, 0, 0);
  }
  const int crow = bm * 128 + wm * 64;
  const int ccol = bn * 64 + wn * 32;
  #pragma unroll
  for (int m = 0; m < 4; m++)
    #pragma unroll
    for (int n = 0; n < 2; n++)
      #pragma unroll
      for (int r = 0; r < 4; r++)
        C[(size_t)(crow + m * 16 + lg * 4 + r) * N + ccol + n * 16 + l15] = acc[m][n][r];
}

// ---------------- prep: rmsnorm + rope + scaling + v transpose [round-6 verbatim] ------
__global__ __launch_bounds__(256) void k_prep(
    const float* __restrict__ qkv, const float* __restrict__ qkve,
    const float* __restrict__ cosT, const float* __restrict__ sinT,
    const float* __restrict__ qnw, const float* __restrict__ knw,
    u16* __restrict__ q_rope, u16* __restrict__ qc,
    u16* __restrict__ k_rope, u16* __restrict__ vT,
    u16* __restrict__ k_enc, u16* __restrict__ vT_enc) {
  const int t = blockIdx.x;
  const int lane = threadIdx.x & 63;
  const int wid = threadIdx.x >> 6;
  const int b = t >> 9, s = t & 511;
  const int d0 = lane, d1 = lane + 64, d2 = lane + 128, d3 = lane + 192;
  const float c0 = cosT[t * HD + d0], c1 = cosT[t * HD + d1], c2 = cosT[t * HD + d2], c3 = cosT[t * HD + d3];
  const float s0 = sinT[t * HD + d0], s1 = sinT[t * HD + d1], s2 = sinT[t * HD + d2], s3 = sinT[t * HD + d3];
  const float qw0 = 1.f + qnw[d0], qw1 = 1.f + qnw[d1], qw2 = 1.f + qnw[d2], qw3 = 1.f + qnw[d3];
  const float kw0 = 1.f + knw[d0], kw1 = 1.f + knw[d1], kw2 = 1.f + knw[d2], kw3 = 1.f + knw[d3];

  // q heads (2 per wave)
  for (int hh = 0; hh < 2; hh++) {
    const int h = wid + hh * 4;
    const float* x = qkv + (size_t)t * 4096 + h * HD;
    float a0 = x[d0], a1 = x[d1], a2 = x[d2], a3 = x[d3];
    float ss = a0 * a0 + a1 * a1 + a2 * a2 + a3 * a3;
    #pragma unroll
    for (int o = 1; o < 64; o <<= 1) ss += __shfl_xor(ss, o);
    const float rms = rsqrtf(ss * (1.f / HD) + EPS_);
    const float n0 = a0 * rms * qw0, n1 = a1 * rms * qw1, n2 = a2 * rms * qw2, n3 = a3 * rms * qw3;
    const size_t qb = ((size_t)t * NH + h) * HD;
    qc[qb + d0] = f2bf(n0 * SCAL); qc[qb + d1] = f2bf(n1 * SCAL);
    qc[qb + d2] = f2bf(n2 * SCAL); qc[qb + d3] = f2bf(n3 * SCAL);
    q_rope[qb + d0] = f2bf((n0 * c0 - n2 * s0) * SCAL);
    q_rope[qb + d1] = f2bf((n1 * c1 - n3 * s1) * SCAL);
    q_rope[qb + d2] = f2bf((n2 * c2 + n0 * s2) * SCAL);
    q_rope[qb + d3] = f2bf((n3 * c3 + n1 * s3) * SCAL);
  }
  // self k head (1 per wave)
  {
    const float* x = qkv + (size_t)t * 4096 + 2048 + wid * HD;
    float a0 = x[d0], a1 = x[d1], a2 = x[d2], a3 = x[d3];
    float ss = a0 * a0 + a1 * a1 + a2 * a2 + a3 * a3;
    #pragma unroll
    for (int o = 1; o < 64; o <<= 1) ss += __shfl_xor(ss, o);
    const float rms = rsqrtf(ss * (1.f / HD) + EPS_);
    const float n0 = a0 * rms * kw0, n1 = a1 * rms * kw1, n2 = a2 * rms * kw2, n3 = a3 * rms * kw3;
    const size_t kb = ((size_t)t * NKV + wid) * HD;
    k_rope[kb + d0] = f2bf(n0 * c0 - n2 * s0);
    k_rope[kb + d1] = f2bf(n1 * c1 - n3 * s1);
    k_rope[kb + d2] = f2bf(n2 * c2 + n0 * s2);
    k_rope[kb + d3] = f2bf(n3 * c3 + n1 * s3);
  }
  // self v -> transposed [b][kvh][d][s]
  {
    const float* x = qkv + (size_t)t * 4096 + 3072 + wid * HD;
    const size_t vb = (size_t)(b * NKV + wid) * HD;
    vT[(vb + d0) * SEQ + s] = f2bf(x[d0]);
    vT[(vb + d1) * SEQ + s] = f2bf(x[d1]);
    vT[(vb + d2) * SEQ + s] = f2bf(x[d2]);
    vT[(vb + d3) * SEQ + s] = f2bf(x[d3]);
  }
  // encoder k (norm, no rope) -- row stride 4096 (lives inside big C)
  {
    const float* x = qkve + (size_t)t * 4096 + wid * HD;
    float a0 = x[d0], a1 = x[d1], a2 = x[d2], a3 = x[d3];
    float ss = a0 * a0 + a1 * a1 + a2 * a2 + a3 * a3;
    #pragma unroll
    for (int o = 1; o < 64; o <<= 1) ss += __shfl_xor(ss, o);
    const float rms = rsqrtf(ss * (1.f / HD) + EPS_);
    const size_t kb = ((size_t)t * NKV + wid) * HD;
    k_enc[kb + d0] = f2bf(a0 * rms * kw0);
    k_enc[kb + d1] = f2bf(a1 * rms * kw1);
    k_enc[kb + d2] = f2bf(a2 * rms * kw2);
    k_enc[kb + d3] = f2bf(a3 * rms * kw3);
  }
  // encoder v -> transposed -- row stride 4096
  {
    const float* x = qkve + (size_t)t * 4096 + 1024 + wid * HD;
    const size_t vb = (size_t)(b * NKV + wid) * HD;
    vT_enc[(vb + d0) * SEQ + s] = f2bf(x[d0]);
    vT_enc[(vb + d1) * SEQ + s] = f2bf(x[d1]);
    vT_enc[(vb + d2) * SEQ + s] = f2bf(x[d2]);
    vT_enc[(vb + d3) * SEQ + s] = f2bf(x[d3]);
  }
}

// ---------------- fused flash attention [round-6 verbatim] ----------------
__global__ __launch_bounds__(256) void k_attn(
    const u16* __restrict__ q_rope, const u16* __restrict__ qc,
    const u16* __restrict__ k_rope, const u16* __restrict__ k_enc,
    const u16* __restrict__ vT, const u16* __restrict__ vT_enc,
    u16* __restrict__ out_bf) {
  __shared__ u16 k_lds[2][64 * 256];
  __shared__ u16 v_lds[2][256 * 64];
  __shared__ u16 p_lds[4][16][72];

  const int qt = blockIdx.x;
  const int h = blockIdx.y;
  const int b = blockIdx.z;
  const int kvh = h >> 1;
  const int tid = threadIdx.x;
  const int lane = tid & 63;
  const int wid = tid >> 6;
  const int l15 = lane & 15;
  const int lg = lane >> 4;
  const int swk = l15 & 7;
  const int qrow = qt * 64 + wid * 16;

  const int nself = qt + 1;
  const int total = nself + 8;

  #define STAGE_TILE(buf, it_)                                                        \
    {                                                                                 \
      const int it = (it_);                                                           \
      const int kt_ = (it < nself) ? it : (it - nself);                               \
      const u16* Kg_ = (it < nself) ? k_rope : k_enc;                                 \
      const u16* Vg_ = (it < nself) ? vT : vT_enc;                                    \
      _Pragma("unroll")                                                               \
      for (int j = 0; j < 8; j++) {                                                   \
        const int idx = j * 256 + tid;                                                \
        const int kr = idx >> 5, kc = idx & 31;                                       \
        const int cs = kc ^ (kr & 7);                                                 \
        gload_lds16(Kg_ + ((size_t)((b * SEQ + kt_ * 64 + kr) * NKV + kvh)) * HD + cs * 8, \
                    &k_lds[buf][idx * 8]);                                            \
      }                                                                               \
      _Pragma("unroll")                                                               \
      for (int j = 0; j < 8; j++) {                                                   \
        const int idx = j * 256 + tid;                                                \
        const int dr = idx >> 3, dc = idx & 7;                                        \
        const int cs = dc ^ (dr & 7);                                                 \
        gload_lds16(Vg_ + ((size_t)((b * NKV + kvh) * HD + dr)) * SEQ + kt_ * 64 + cs * 8, \
                    &v_lds[buf][idx * 8]);                                            \
      }                                                                               \
    }

  bf16x8 qf[8];
  {
    const size_t base = ((size_t)(b * SEQ + qrow + l15) * NH + h) * HD + lg * 8;
    #pragma unroll
    for (int c = 0; c < 8; c++) qf[c] = *(const bf16x8*)(q_rope + base + c * 32);
  }

  float m[4], lsum[4];
  f32x4 O[16], Os[16];
  #pragma unroll
  for (int r = 0; r < 4; r++) { m[r] = -INFINITY; lsum[r] = 0.f; }
  #pragma unroll
  for (int d = 0; d < 16; d++) { O[d] = (f32x4){0.f, 0.f, 0.f, 0.f}; Os[d] = O[d]; }

  STAGE_TILE(0, 0);
  int cur = 0;

  for (int it = 0; it < total; ++it) {
    __syncthreads();
    if (it + 1 < total) STAGE_TILE(cur ^ 1, it + 1);

    if (it == nself) {
      #pragma unroll
      for (int r = 0; r < 4; r++) {
        const float inv = 1.f / lsum[r];
        #pragma unroll
        for (int d = 0; d < 16; d++) Os[d][r] = O[d][r] * inv;
        m[r] = -INFINITY; lsum[r] = 0.f;
      }
      #pragma unroll
      for (int d = 0; d < 16; d++) O[d] = (f32x4){0.f, 0.f, 0.f, 0.f};
      const size_t base = ((size_t)(b * SEQ + qrow + l15) * NH + h) * HD + lg * 8;
      #pragma unroll
      for (int c = 0; c < 8; c++) qf[c] = *(const bf16x8*)(qc + base + c * 32);
    }

    const u16* kl = k_lds[cur];
    const u16* vl = v_lds[cur];

    f32x4 sc[4];
    #pragma unroll
    for (int n = 0; n < 4; n++) sc[n] = (f32x4){0.f, 0.f, 0.f, 0.f};
    #pragma unroll
    for (int n = 0; n < 4; n++) {
      const int krow = n * 16 + l15;
      #pragma unroll
      for (int c = 0; c < 8; c++) {
        bf16x8 kf = *(const bf16x8*)&kl[krow * 256 + (((c * 4 + lg) ^ swk) * 8)];
        sc[n] = __builtin_amdgcn_mfma_f32_16x16x32_bf16(qf[c], kf, sc[n], 0, 0, 0);
      }
    }
    if (it == qt && it < nself) {
      #pragma unroll
      for (int n = 0; n < 4; n++) {
        const int key = qt * 64 + n * 16 + l15;
        #pragma unroll
        for (int r = 0; r < 4; r++)
          if (key > qrow + lg * 4 + r) sc[n][r] = -INFINITY;
      }
    }
    float pmax[4];
    #pragma unroll
    for (int r = 0; r < 4; r++)
      pmax[r] = fmaxf(fmaxf(sc[0][r], sc[1][r]), fmaxf(sc[2][r], sc[3][r]));
    #pragma unroll
    for (int off = 1; off < 16; off <<= 1)
      #pragma unroll
      for (int r = 0; r < 4; r++) pmax[r] = fmaxf(pmax[r], __shfl_xor(pmax[r], off));
    float scal[4];
    #pragma unroll
    for (int r = 0; r < 4; r++) {
      const float mn = fmaxf(m[r], pmax[r]);
      scal[r] = __expf(m[r] - mn);
      m[r] = mn;
    }
    float ps[4] = {0.f, 0.f, 0.f, 0.f};
    #pragma unroll
    for (int n = 0; n < 4; n++)
      #pragma unroll
      for (int r = 0; r < 4; r++) {
        const float p = __expf(sc[n][r] - m[r]);
        ps[r] += p;
        p_lds[wid][lg * 4 + r][n * 16 + l15] = f2bf(p);
      }
    #pragma unroll
    for (int off = 1; off < 16; off <<= 1)
      #pragma unroll
      for (int r = 0; r < 4; r++) ps[r] += __shfl_xor(ps[r], off);
    #pragma unroll
    for (int r = 0; r < 4; r++) lsum[r] = lsum[r] * scal[r] + ps[r];
    #pragma unroll
    for (int d = 0; d < 16; d++)
      #pragma unroll
      for (int r = 0; r < 4; r++) O[d][r] *= scal[r];
    bf16x8 pa0 = *(const bf16x8*)&p_lds[wid][l15][lg * 8];
    bf16x8 pa1 = *(const bf16x8*)&p_lds[wid][l15][32 + lg * 8];
    #pragma unroll
    for (int d = 0; d < 16; d++) {
      const int vrow = d * 16 + l15;
      bf16x8 v0 = *(const bf16x8*)&vl[vrow * 64 + ((lg ^ swk) * 8)];
      bf16x8 v1 = *(const bf16x8*)&vl[vrow * 64 + (((lg + 4) ^ swk) * 8)];
      O[d] = __builtin_amdgcn_mfma_f32_16x16x32_bf16(pa0, v0, O[d], 0, 0, 0);
      O[d] = __builtin_amdgcn_mfma_f32_16x16x32_bf16(pa1, v1, O[d], 0, 0, 0);
    }
    cur ^= 1;
  }
  #undef STAGE_TILE

  #pragma unroll
  for (int r = 0; r < 4; r++) {
    const float inv = 1.f / lsum[r];
    const size_t rowb = (size_t)(b * SEQ + qrow + lg * 4 + r) * (NH * HD) + h * HD;
    #pragma unroll
    for (int d = 0; d < 16; d++)
      out_bf[rowb + d * 16 + l15] = f2bf(Os[d][r] + O[d][r] * inv);
  }
}

// ---------------- launcher ----------------
extern "C" void kernel_launch(void* const* d_in, const int* in_sizes, int n_in,
                              void* d_out, int out_size, void* d_ws, size_t ws_size,
                              hipStream_t stream) {
  (void)in_sizes; (void)n_in; (void)out_size; (void)ws_size;
  const float* hidden  = (const float*)d_in[0];
  const float* encoder = (const float*)d_in[1];
  const float* cosT    = (const float*)d_in[2];
  const float* sinT    = (const float*)d_in[3];
  const float* w_qkv   = (const float*)d_in[4];
  const float* w_o     = (const float*)d_in[5];
  const float* qnw     = (const float*)d_in[6];
  const float* knw     = (const float*)d_in[7];
  float* out = (float*)d_out;
  char* ws = (char*)d_ws;

  // ws layout (MB offsets), max touch 104 MB [round-6 verbatim]
  u16*  hid_bf = (u16*) (ws + (0ull  << 20));   // 8 MB   } contiguous: A2 = [hidden; encoder]
  u16*  enc_bf = (u16*) (ws + (8ull  << 20));   // 8 MB   }   (4096 x 2048 bf16)
  u16*  wqkvT  = (u16*) (ws + (16ull << 20));   // 16 MB  [dies after big GEMM]
  u16*  woT    = (u16*) (ws + (32ull << 20));   // 8 MB   [lives to out-proj]
  float* qkvC  = (float*)(ws + (40ull << 20));  // 64 MB  (4096x4096 f32) [dies after prep]
  u16*  q_rope = (u16*) (ws + (0ull  << 20));   // 8 MB   (overlays dead hid_bf)
  u16*  qc     = (u16*) (ws + (8ull  << 20));   // 8 MB   (overlays dead enc_bf)
  u16*  k_rope = (u16*) (ws + (16ull << 20));   // 4 MB   (overlays dead wqkvT)
  u16*  vT     = (u16*) (ws + (20ull << 20));   // 4 MB
  u16*  k_enc  = (u16*) (ws + (24ull << 20));   // 4 MB
  u16*  vT_enc = (u16*) (ws + (28ull << 20));   // 4 MB
  u16*  attnbf = (u16*) (ws + (40ull << 20));   // 8 MB   (overlays dead qkvC head)

  const int n8 = T_N * 2048 / 8;
  k_f32_to_bf16<<<n8 / 256, 256, 0, stream>>>(hidden, hid_bf, n8);
  k_f32_to_bf16<<<n8 / 256, 256, 0, stream>>>(encoder, enc_bf, n8);
  k_transpose_bf16<<<dim3(4096 / 32, 2048 / 32), dim3(32, 8), 0, stream>>>(w_qkv, wqkvT, 2048, 4096);
  k_transpose_bf16<<<dim3(2048 / 32, 2048 / 32), dim3(32, 8), 0, stream>>>(w_o, woT, 2048, 2048);
  // one big GEMM: [hidden; encoder] (4096x2048) @ w_qkv^T -> qkvC (4096x4096)
  k_gemm_bt<<<dim3(32, 32), 256, 0, stream>>>(hid_bf, wqkvT, qkvC, 4096, 4096, 2048);
  // enc rows' kv outputs live at qkvC[2048 + t][2048 + c], row stride 4096
  k_prep<<<T_N, 256, 0, stream>>>(qkvC, qkvC + (size_t)2048 * 4096 + 2048,
                                  cosT, sinT, qnw, knw,
                                  q_rope, qc, k_rope, vT, k_enc, vT_enc);
  k_attn<<<dim3(8, 8, 4), 256, 0, stream>>>(q_rope, qc, k_rope, k_enc, vT, vT_enc, attnbf);
  // out-projection: 128x64 tiles, grid (16,32) -> 512 blocks (2 blocks/CU)
  k_gemm_n64<<<dim3(16, 32), 256, 0, stream>>>(attnbf, woT, out);
}

// Round 12
// 249.030 us; speedup vs baseline: 1.7282x; 1.0005x over previous
//
#include <hip/hip_runtime.h>
#include <hip/hip_bf16.h>

// ---------------- types / constants ----------------
typedef __bf16 bf16x8 __attribute__((ext_vector_type(8)));
typedef float f32x4 __attribute__((ext_vector_type(4)));
typedef unsigned short u16;
typedef u16 u16x8 __attribute__((ext_vector_type(8)));

#define T_N 2048
#define NH 8
#define NKV 4
#define HD 256
#define SEQ 512
#define SCAL 0.0625f   // 256^-0.5
#define EPS_ 1e-6f

typedef const __attribute__((address_space(1))) void* gptr1;
typedef __attribute__((address_space(3))) void* lptr3;

__device__ __forceinline__ u16 f2bf(float f) {
  union { float f; unsigned u; } x; x.f = f;
  unsigned r = x.u + 0x7fffu + ((x.u >> 16) & 1u);
  return (u16)(r >> 16);
}
__device__ __forceinline__ void gload_lds16(const void* g, void* l) {
  __builtin_amdgcn_global_load_lds((gptr1)g, (lptr3)l, 16, 0, 0);
}

// ---------------- f32 -> bf16 convert (vectorized) [round-8 verbatim] ----------------
__global__ void k_f32_to_bf16(const float* __restrict__ in, u16* __restrict__ out, int n8) {
  int i = blockIdx.x * blockDim.x + threadIdx.x;
  if (i >= n8) return;
  const float4* p = (const float4*)in + (size_t)i * 2;
  float4 v0 = p[0], v1 = p[1];
  u16x8 o;
  o[0] = f2bf(v0.x); o[1] = f2bf(v0.y); o[2] = f2bf(v0.z); o[3] = f2bf(v0.w);
  o[4] = f2bf(v1.x); o[5] = f2bf(v1.y); o[6] = f2bf(v1.z); o[7] = f2bf(v1.w);
  *(u16x8*)(out + (size_t)i * 8) = o;
}

// ---------------- transpose f32 (R,C) -> bf16 (C,R) [round-8 verbatim] ----------------
__global__ void k_transpose_bf16(const float* __restrict__ in, u16* __restrict__ out, int R, int C) {
  __shared__ float tile[32][33];
  const int tx = threadIdx.x, ty = threadIdx.y;
  const int c0 = blockIdx.x * 32, r0 = blockIdx.y * 32;
  #pragma unroll
  for (int i = ty; i < 32; i += 8) tile[i][tx] = in[(size_t)(r0 + i) * C + c0 + tx];
  __syncthreads();
  #pragma unroll
  for (int i = ty; i < 32; i += 8) out[(size_t)(c0 + i) * R + r0 + tx] = f2bf(tile[tx][i]);
}

// ---------------- bf16 GEMM: C[M,N] = A[M,K] * Bt[N,K]^T [round-8 verbatim] ----------------
__global__ __launch_bounds__(256) void k_gemm_bt(const u16* __restrict__ A, const u16* __restrict__ Bt,
                                                 float* __restrict__ C, int M, int N, int K) {
  __shared__ u16 a_lds[128 * 32];
  __shared__ u16 b_lds[128 * 32];
  const int tid = threadIdx.x;
  const int lane = tid & 63;
  const int wid = tid >> 6;
  const int l15 = lane & 15, lg = lane >> 4;
  const int bm = blockIdx.x, bn = blockIdx.y;
  const int wm = wid >> 1, wn = wid & 1;
  f32x4 acc[4][4];
  #pragma unroll
  for (int i = 0; i < 4; i++)
    #pragma unroll
    for (int j = 0; j < 4; j++) acc[i][j] = (f32x4){0.f, 0.f, 0.f, 0.f};
  const int e = tid * 8;                // element offset within 64-row half-tile
  const int row0 = e >> 5, col0 = e & 31;
  const u16* Ab = A + (size_t)bm * 128 * K;
  const u16* Bb = Bt + (size_t)bn * 128 * K;
  for (int kt = 0; kt < K; kt += 32) {
    __syncthreads();
    gload_lds16(Ab + (size_t)row0 * K + kt + col0, &a_lds[e]);
    gload_lds16(Ab + (size_t)(row0 + 64) * K + kt + col0, &a_lds[e + 2048]);
    gload_lds16(Bb + (size_t)row0 * K + kt + col0, &b_lds[e]);
    gload_lds16(Bb + (size_t)(row0 + 64) * K + kt + col0, &b_lds[e + 2048]);
    __syncthreads();
    bf16x8 af[4], bfr[4];
    #pragma unroll
    for (int m = 0; m < 4; m++) af[m] = *(const bf16x8*)&a_lds[(wm * 64 + m * 16 + l15) * 32 + lg * 8];
    #pragma unroll
    for (int n = 0; n < 4; n++) bfr[n] = *(const bf16x8*)&b_lds[(wn * 64 + n * 16 + l15) * 32 + lg * 8];
    #pragma unroll
    for (int m = 0; m < 4; m++)
      #pragma unroll
      for (int n = 0; n < 4; n++)
        acc[m][n] = __builtin_amdgcn_mfma_f32_16x16x32_bf16(af[m], bfr[n], acc[m][n], 0, 0, 0);
  }
  const int crow = bm * 128 + wm * 64;
  const int ccol = bn * 128 + wn * 64;
  #pragma unroll
  for (int m = 0; m < 4; m++)
    #pragma unroll
    for (int n = 0; n < 4; n++)
      #pragma unroll
      for (int r = 0; r < 4; r++)
        C[(size_t)(crow + m * 16 + lg * 4 + r) * N + ccol + n * 16 + l15] = acc[m][n][r];
}

// ---------------- out-projection GEMM, 128x64 tile [round-8 verbatim] ----------------
__global__ __launch_bounds__(256) void k_gemm_n64(const u16* __restrict__ A, const u16* __restrict__ Bt,
                                                  float* __restrict__ C) {
  __shared__ u16 a_lds[128 * 32];
  __shared__ u16 b_lds[64 * 32];
  const int N = 2048, K = 2048;
  const int tid = threadIdx.x;
  const int lane = tid & 63;
  const int wid = tid >> 6;
  const int l15 = lane & 15, lg = lane >> 4;
  const int bm = blockIdx.x, bn = blockIdx.y;
  const int wm = wid >> 1, wn = wid & 1;
  f32x4 acc[4][2];
  #pragma unroll
  for (int i = 0; i < 4; i++)
    #pragma unroll
    for (int j = 0; j < 2; j++) acc[i][j] = (f32x4){0.f, 0.f, 0.f, 0.f};
  const int e = tid * 8;                    // 2048 elems = 64 rows x 32 cols
  const int row0 = e >> 5, col0 = e & 31;   // row0 0..63
  const u16* Ab = A + (size_t)bm * 128 * K;
  const u16* Bb = Bt + (size_t)bn * 64 * K;
  for (int kt = 0; kt < K; kt += 32) {
    __syncthreads();
    gload_lds16(Ab + (size_t)row0 * K + kt + col0, &a_lds[e]);
    gload_lds16(Ab + (size_t)(row0 + 64) * K + kt + col0, &a_lds[e + 2048]);
    gload_lds16(Bb + (size_t)row0 * K + kt + col0, &b_lds[e]);
    __syncthreads();
    bf16x8 af[4], bfr[2];
    #pragma unroll
    for (int m = 0; m < 4; m++) af[m] = *(const bf16x8*)&a_lds[(wm * 64 + m * 16 + l15) * 32 + lg * 8];
    #pragma unroll
    for (int n = 0; n < 2; n++) bfr[n] = *(const bf16x8*)&b_lds[(wn * 32 + n * 16 + l15) * 32 + lg * 8];
    #pragma unroll
    for (int m = 0; m < 4; m++)
      #pragma unroll
      for (int n = 0; n < 2; n++)
        acc[m][n] = __builtin_amdgcn_mfma_f32_16x16x32_bf16(af[m], bfr[n], acc[m][n], 0, 0, 0);
  }
  const int crow = bm * 128 + wm * 64;
  const int ccol = bn * 64 + wn * 32;
  #pragma unroll
  for (int m = 0; m < 4; m++)
    #pragma unroll
    for (int n = 0; n < 2; n++)
      #pragma unroll
      for (int r = 0; r < 4; r++)
        C[(size_t)(crow + m * 16 + lg * 4 + r) * N + ccol + n * 16 + l15] = acc[m][n][r];
}

// ---------------- prep: rmsnorm + rope + scaling + v transpose [round-8 verbatim] ------
__global__ __launch_bounds__(256) void k_prep(
    const float* __restrict__ qkv, const float* __restrict__ qkve,
    const float* __restrict__ cosT, const float* __restrict__ sinT,
    const float* __restrict__ qnw, const float* __restrict__ knw,
    u16* __restrict__ q_rope, u16* __restrict__ qc,
    u16* __restrict__ k_rope, u16* __restrict__ vT,
    u16* __restrict__ k_enc, u16* __restrict__ vT_enc) {
  const int t = blockIdx.x;
  const int lane = threadIdx.x & 63;
  const int wid = threadIdx.x >> 6;
  const int b = t >> 9, s = t & 511;
  const int d0 = lane, d1 = lane + 64, d2 = lane + 128, d3 = lane + 192;
  const float c0 = cosT[t * HD + d0], c1 = cosT[t * HD + d1], c2 = cosT[t * HD + d2], c3 = cosT[t * HD + d3];
  const float s0 = sinT[t * HD + d0], s1 = sinT[t * HD + d1], s2 = sinT[t * HD + d2], s3 = sinT[t * HD + d3];
  const float qw0 = 1.f + qnw[d0], qw1 = 1.f + qnw[d1], qw2 = 1.f + qnw[d2], qw3 = 1.f + qnw[d3];
  const float kw0 = 1.f + knw[d0], kw1 = 1.f + knw[d1], kw2 = 1.f + knw[d2], kw3 = 1.f + knw[d3];

  // q heads (2 per wave)
  for (int hh = 0; hh < 2; hh++) {
    const int h = wid + hh * 4;
    const float* x = qkv + (size_t)t * 4096 + h * HD;
    float a0 = x[d0], a1 = x[d1], a2 = x[d2], a3 = x[d3];
    float ss = a0 * a0 + a1 * a1 + a2 * a2 + a3 * a3;
    #pragma unroll
    for (int o = 1; o < 64; o <<= 1) ss += __shfl_xor(ss, o);
    const float rms = rsqrtf(ss * (1.f / HD) + EPS_);
    const float n0 = a0 * rms * qw0, n1 = a1 * rms * qw1, n2 = a2 * rms * qw2, n3 = a3 * rms * qw3;
    const size_t qb = ((size_t)t * NH + h) * HD;
    qc[qb + d0] = f2bf(n0 * SCAL); qc[qb + d1] = f2bf(n1 * SCAL);
    qc[qb + d2] = f2bf(n2 * SCAL); qc[qb + d3] = f2bf(n3 * SCAL);
    q_rope[qb + d0] = f2bf((n0 * c0 - n2 * s0) * SCAL);
    q_rope[qb + d1] = f2bf((n1 * c1 - n3 * s1) * SCAL);
    q_rope[qb + d2] = f2bf((n2 * c2 + n0 * s2) * SCAL);
    q_rope[qb + d3] = f2bf((n3 * c3 + n1 * s3) * SCAL);
  }
  // self k head (1 per wave)
  {
    const float* x = qkv + (size_t)t * 4096 + 2048 + wid * HD;
    float a0 = x[d0], a1 = x[d1], a2 = x[d2], a3 = x[d3];
    float ss = a0 * a0 + a1 * a1 + a2 * a2 + a3 * a3;
    #pragma unroll
    for (int o = 1; o < 64; o <<= 1) ss += __shfl_xor(ss, o);
    const float rms = rsqrtf(ss * (1.f / HD) + EPS_);
    const float n0 = a0 * rms * kw0, n1 = a1 * rms * kw1, n2 = a2 * rms * kw2, n3 = a3 * rms * kw3;
    const size_t kb = ((size_t)t * NKV + wid) * HD;
    k_rope[kb + d0] = f2bf(n0 * c0 - n2 * s0);
    k_rope[kb + d1] = f2bf(n1 * c1 - n3 * s1);
    k_rope[kb + d2] = f2bf(n2 * c2 + n0 * s2);
    k_rope[kb + d3] = f2bf(n3 * c3 + n1 * s3);
  }
  // self v -> transposed [b][kvh][d][s]
  {
    const float* x = qkv + (size_t)t * 4096 + 3072 + wid * HD;
    const size_t vb = (size_t)(b * NKV + wid) * HD;
    vT[(vb + d0) * SEQ + s] = f2bf(x[d0]);
    vT[(vb + d1) * SEQ + s] = f2bf(x[d1]);
    vT[(vb + d2) * SEQ + s] = f2bf(x[d2]);
    vT[(vb + d3) * SEQ + s] = f2bf(x[d3]);
  }
  // encoder k (norm, no rope) -- row stride 4096 (lives inside big C)
  {
    const float* x = qkve + (size_t)t * 4096 + wid * HD;
    float a0 = x[d0], a1 = x[d1], a2 = x[d2], a3 = x[d3];
    float ss = a0 * a0 + a1 * a1 + a2 * a2 + a3 * a3;
    #pragma unroll
    for (int o = 1; o < 64; o <<= 1) ss += __shfl_xor(ss, o);
    const float rms = rsqrtf(ss * (1.f / HD) + EPS_);
    const size_t kb = ((size_t)t * NKV + wid) * HD;
    k_enc[kb + d0] = f2bf(a0 * rms * kw0);
    k_enc[kb + d1] = f2bf(a1 * rms * kw1);
    k_enc[kb + d2] = f2bf(a2 * rms * kw2);
    k_enc[kb + d3] = f2bf(a3 * rms * kw3);
  }
  // encoder v -> transposed -- row stride 4096
  {
    const float* x = qkve + (size_t)t * 4096 + 1024 + wid * HD;
    const size_t vb = (size_t)(b * NKV + wid) * HD;
    vT_enc[(vb + d0) * SEQ + s] = f2bf(x[d0]);
    vT_enc[(vb + d1) * SEQ + s] = f2bf(x[d1]);
    vT_enc[(vb + d2) * SEQ + s] = f2bf(x[d2]);
    vT_enc[(vb + d3) * SEQ + s] = f2bf(x[d3]);
  }
}

// ---------------- fused flash attention [round-8 verbatim] ----------------
__global__ __launch_bounds__(256) void k_attn(
    const u16* __restrict__ q_rope, const u16* __restrict__ qc,
    const u16* __restrict__ k_rope, const u16* __restrict__ k_enc,
    const u16* __restrict__ vT, const u16* __restrict__ vT_enc,
    u16* __restrict__ out_bf) {
  __shared__ u16 k_lds[2][64 * 256];
  __shared__ u16 v_lds[2][256 * 64];
  __shared__ u16 p_lds[4][16][72];

  const int qt = blockIdx.x;
  const int h = blockIdx.y;
  const int b = blockIdx.z;
  const int kvh = h >> 1;
  const int tid = threadIdx.x;
  const int lane = tid & 63;
  const int wid = tid >> 6;
  const int l15 = lane & 15;
  const int lg = lane >> 4;
  const int swk = l15 & 7;
  const int qrow = qt * 64 + wid * 16;

  const int nself = qt + 1;
  const int total = nself + 8;

  #define STAGE_TILE(buf, it_)                                                        \
    {                                                                                 \
      const int it = (it_);                                                           \
      const int kt_ = (it < nself) ? it : (it - nself);                               \
      const u16* Kg_ = (it < nself) ? k_rope : k_enc;                                 \
      const u16* Vg_ = (it < nself) ? vT : vT_enc;                                    \
      _Pragma("unroll")                                                               \
      for (int j = 0; j < 8; j++) {                                                   \
        const int idx = j * 256 + tid;                                                \
        const int kr = idx >> 5, kc = idx & 31;                                       \
        const int cs = kc ^ (kr & 7);                                                 \
        gload_lds16(Kg_ + ((size_t)((b * SEQ + kt_ * 64 + kr) * NKV + kvh)) * HD + cs * 8, \
                    &k_lds[buf][idx * 8]);                                            \
      }                                                                               \
      _Pragma("unroll")                                                               \
      for (int j = 0; j < 8; j++) {                                                   \
        const int idx = j * 256 + tid;                                                \
        const int dr = idx >> 3, dc = idx & 7;                                        \
        const int cs = dc ^ (dr & 7);                                                 \
        gload_lds16(Vg_ + ((size_t)((b * NKV + kvh) * HD + dr)) * SEQ + kt_ * 64 + cs * 8, \
                    &v_lds[buf][idx * 8]);                                            \
      }                                                                               \
    }

  bf16x8 qf[8];
  {
    const size_t base = ((size_t)(b * SEQ + qrow + l15) * NH + h) * HD + lg * 8;
    #pragma unroll
    for (int c = 0; c < 8; c++) qf[c] = *(const bf16x8*)(q_rope + base + c * 32);
  }

  float m[4], lsum[4];
  f32x4 O[16], Os[16];
  #pragma unroll
  for (int r = 0; r < 4; r++) { m[r] = -INFINITY; lsum[r] = 0.f; }
  #pragma unroll
  for (int d = 0; d < 16; d++) { O[d] = (f32x4){0.f, 0.f, 0.f, 0.f}; Os[d] = O[d]; }

  STAGE_TILE(0, 0);
  int cur = 0;

  for (int it = 0; it < total; ++it) {
    __syncthreads();
    if (it + 1 < total) STAGE_TILE(cur ^ 1, it + 1);

    if (it == nself) {
      #pragma unroll
      for (int r = 0; r < 4; r++) {
        const float inv = 1.f / lsum[r];
        #pragma unroll
        for (int d = 0; d < 16; d++) Os[d][r] = O[d][r] * inv;
        m[r] = -INFINITY; lsum[r] = 0.f;
      }
      #pragma unroll
      for (int d = 0; d < 16; d++) O[d] = (f32x4){0.f, 0.f, 0.f, 0.f};
      const size_t base = ((size_t)(b * SEQ + qrow + l15) * NH + h) * HD + lg * 8;
      #pragma unroll
      for (int c = 0; c < 8; c++) qf[c] = *(const bf16x8*)(qc + base + c * 32);
    }

    const u16* kl = k_lds[cur];
    const u16* vl = v_lds[cur];

    f32x4 sc[4];
    #pragma unroll
    for (int n = 0; n < 4; n++) sc[n] = (f32x4){0.f, 0.f, 0.f, 0.f};
    #pragma unroll
    for (int n = 0; n < 4; n++) {
      const int krow = n * 16 + l15;
      #pragma unroll
      for (int c = 0; c < 8; c++) {
        bf16x8 kf = *(const bf16x8*)&kl[krow * 256 + (((c * 4 + lg) ^ swk) * 8)];
        sc[n] = __builtin_amdgcn_mfma_f32_16x16x32_bf16(qf[c], kf, sc[n], 0, 0, 0);
      }
    }
    if (it == qt && it < nself) {
      #pragma unroll
      for (int n = 0; n < 4; n++) {
        const int key = qt * 64 + n * 16 + l15;
        #pragma unroll
        for (int r = 0; r < 4; r++)
          if (key > qrow + lg * 4 + r) sc[n][r] = -INFINITY;
      }
    }
    float pmax[4];
    #pragma unroll
    for (int r = 0; r < 4; r++)
      pmax[r] = fmaxf(fmaxf(sc[0][r], sc[1][r]), fmaxf(sc[2][r], sc[3][r]));
    #pragma unroll
    for (int off = 1; off < 16; off <<= 1)
      #pragma unroll
      for (int r = 0; r < 4; r++) pmax[r] = fmaxf(pmax[r], __shfl_xor(pmax[r], off));
    float scal[4];
    #pragma unroll
    for (int r = 0; r < 4; r++) {
      const float mn = fmaxf(m[r], pmax[r]);
      scal[r] = __expf(m[r] - mn);
      m[r] = mn;
    }
    float ps[4] = {0.f, 0.f, 0.f, 0.f};
    #pragma unroll
    for (int n = 0; n < 4; n++)
      #pragma unroll
      for (int r = 0; r < 4; r++) {
        const float p = __expf(sc[n][r] - m[r]);
        ps[r] += p;
        p_lds[wid][lg * 4 + r][n * 16 + l15] = f2bf(p);
      }
    #pragma unroll
    for (int off = 1; off < 16; off <<= 1)
      #pragma unroll
      for (int r = 0; r < 4; r++) ps[r] += __shfl_xor(ps[r], off);
    #pragma unroll
    for (int r = 0; r < 4; r++) lsum[r] = lsum[r] * scal[r] + ps[r];
    #pragma unroll
    for (int d = 0; d < 16; d++)
      #pragma unroll
      for (int r = 0; r < 4; r++) O[d][r] *= scal[r];
    bf16x8 pa0 = *(const bf16x8*)&p_lds[wid][l15][lg * 8];
    bf16x8 pa1 = *(const bf16x8*)&p_lds[wid][l15][32 + lg * 8];
    #pragma unroll
    for (int d = 0; d < 16; d++) {
      const int vrow = d * 16 + l15;
      bf16x8 v0 = *(const bf16x8*)&vl[vrow * 64 + ((lg ^ swk) * 8)];
      bf16x8 v1 = *(const bf16x8*)&vl[vrow * 64 + (((lg + 4) ^ swk) * 8)];
      O[d] = __builtin_amdgcn_mfma_f32_16x16x32_bf16(pa0, v0, O[d], 0, 0, 0);
      O[d] = __builtin_amdgcn_mfma_f32_16x16x32_bf16(pa1, v1, O[d], 0, 0, 0);
    }
    cur ^= 1;
  }
  #undef STAGE_TILE

  #pragma unroll
  for (int r = 0; r < 4; r++) {
    const float inv = 1.f / lsum[r];
    const size_t rowb = (size_t)(b * SEQ + qrow + lg * 4 + r) * (NH * HD) + h * HD;
    #pragma unroll
    for (int d = 0; d < 16; d++)
      out_bf[rowb + d * 16 + l15] = f2bf(Os[d][r] + O[d][r] * inv);
  }
}

// ---------------- launcher [round-8 verbatim] ----------------
extern "C" void kernel_launch(void* const* d_in, const int* in_sizes, int n_in,
                              void* d_out, int out_size, void* d_ws, size_t ws_size,
                              hipStream_t stream) {
  (void)in_sizes; (void)n_in; (void)out_size; (void)ws_size;
  const float* hidden  = (const float*)d_in[0];
  const float* encoder = (const float*)d_in[1];
  const float* cosT    = (const float*)d_in[2];
  const float* sinT    = (const float*)d_in[3];
  const float* w_qkv   = (const float*)d_in[4];
  const float* w_o     = (const float*)d_in[5];
  const float* qnw     = (const float*)d_in[6];
  const float* knw     = (const float*)d_in[7];
  float* out = (float*)d_out;
  char* ws = (char*)d_ws;

  // ws layout (MB offsets), max touch 104 MB [round-8 verbatim]
  u16*  hid_bf = (u16*) (ws + (0ull  << 20));   // 8 MB   } contiguous: A2 = [hidden; encoder]
  u16*  enc_bf = (u16*) (ws + (8ull  << 20));   // 8 MB   }   (4096 x 2048 bf16)
  u16*  wqkvT  = (u16*) (ws + (16ull << 20));   // 16 MB  [dies after big GEMM]
  u16*  woT    = (u16*) (ws + (32ull << 20));   // 8 MB   [lives to out-proj]
  float* qkvC  = (float*)(ws + (40ull << 20));  // 64 MB  (4096x4096 f32) [dies after prep]
  u16*  q_rope = (u16*) (ws + (0ull  << 20));   // 8 MB   (overlays dead hid_bf)
  u16*  qc     = (u16*) (ws + (8ull  << 20));   // 8 MB   (overlays dead enc_bf)
  u16*  k_rope = (u16*) (ws + (16ull << 20));   // 4 MB   (overlays dead wqkvT)
  u16*  vT     = (u16*) (ws + (20ull << 20));   // 4 MB
  u16*  k_enc  = (u16*) (ws + (24ull << 20));   // 4 MB
  u16*  vT_enc = (u16*) (ws + (28ull << 20));   // 4 MB
  u16*  attnbf = (u16*) (ws + (40ull << 20));   // 8 MB   (overlays dead qkvC head)

  const int n8 = T_N * 2048 / 8;
  k_f32_to_bf16<<<n8 / 256, 256, 0, stream>>>(hidden, hid_bf, n8);
  k_f32_to_bf16<<<n8 / 256, 256, 0, stream>>>(encoder, enc_bf, n8);
  k_transpose_bf16<<<dim3(4096 / 32, 2048 / 32), dim3(32, 8), 0, stream>>>(w_qkv, wqkvT, 2048, 4096);
  k_transpose_bf16<<<dim3(2048 / 32, 2048 / 32), dim3(32, 8), 0, stream>>>(w_o, woT, 2048, 2048);
  // one big GEMM: [hidden; encoder] (4096x2048) @ w_qkv^T -> qkvC (4096x4096)
  k_gemm_bt<<<dim3(32, 32), 256, 0, stream>>>(hid_bf, wqkvT, qkvC, 4096, 4096, 2048);
  // enc rows' kv outputs live at qkvC[2048 + t][2048 + c], row stride 4096
  k_prep<<<T_N, 256, 0, stream>>>(qkvC, qkvC + (size_t)2048 * 4096 + 2048,
                                  cosT, sinT, qnw, knw,
                                  q_rope, qc, k_rope, vT, k_enc, vT_enc);
  k_attn<<<dim3(8, 8, 4), 256, 0, stream>>>(q_rope, qc, k_rope, k_enc, vT, vT_enc, attnbf);
  // out-projection: 128x64 tiles, grid (16,32) -> 512 blocks (2 blocks/CU)
  k_gemm_n64<<<dim3(16, 32), 256, 0, stream>>>(attnbf, woT, out);
}